// Round 6
// baseline (977.532 us; speedup 1.0000x reference)
//
#include <hip/hip_runtime.h>

typedef __bf16 bf16_t;
typedef __bf16 bf16x8 __attribute__((ext_vector_type(8)));
typedef float f32x4 __attribute__((ext_vector_type(4)));

#define LN_EPS 1e-3f

__device__ __forceinline__ void gload_lds16(const void* g, void* l) {
    __builtin_amdgcn_global_load_lds(
        (__attribute__((address_space(1))) void*)(g),
        (__attribute__((address_space(3))) void*)(l), 16, 0, 0);
}

// ---------------- weight prep ----------------
// out[(sel*1024 + h*64 + d)*1024 + c] = w_sel[h][c][d]
__global__ void pack_qkv_w(const float* __restrict__ wq, const float* __restrict__ wk,
                           const float* __restrict__ wv, bf16_t* __restrict__ outp)
{
    int idx = blockIdx.x * 256 + threadIdx.x;       // 0 .. 3*1024*1024-1
    int c   = idx & 1023;
    int n   = idx >> 10;
    int sel = n >> 10;
    int hd  = n & 1023;
    const float* src = (sel == 0) ? wq : (sel == 1) ? wk : wv;
    outp[idx] = (bf16_t)src[((hd >> 6) * 1024 + c) * 64 + (hd & 63)];
}

// out[n*K + k] = in[k*N + n]   (K = 1<<lgK, N = 1<<lgN)
__global__ void transpose_w(const float* __restrict__ in, bf16_t* __restrict__ outp,
                            int lgK, int lgN)
{
    long idx = (long)blockIdx.x * 256 + threadIdx.x;
    long k = idx & ((1L << lgK) - 1);
    long n = idx >> lgK;
    outp[idx] = (bf16_t)in[n + (k << lgN)];
}

// ---------------- layernorm (f32 in -> bf16 LN out) ----------------
__global__ __launch_bounds__(256)
void ln_fwd(const float* __restrict__ in, const float* __restrict__ g,
            const float* __restrict__ be, bf16_t* __restrict__ outp)
{
    const long row = blockIdx.x;
    const int t = threadIdx.x;
    float4 v = ((const float4*)(in + row * 1024))[t];
    float s  = v.x + v.y + v.z + v.w;
    float sq = v.x * v.x + v.y * v.y + v.z * v.z + v.w * v.w;
#pragma unroll
    for (int off = 1; off < 64; off <<= 1) {
        s  += __shfl_xor(s, off);
        sq += __shfl_xor(sq, off);
    }
    __shared__ float red[8];
    if ((t & 63) == 0) { red[(t >> 6) * 2] = s; red[(t >> 6) * 2 + 1] = sq; }
    __syncthreads();
    s  = red[0] + red[2] + red[4] + red[6];
    sq = red[1] + red[3] + red[5] + red[7];
    float mean = s * 0.0009765625f;
    float var  = sq * 0.0009765625f - mean * mean;
    float rstd = rsqrtf(var + LN_EPS);
    float4 gv = ((const float4*)g)[t];
    float4 bv = ((const float4*)be)[t];
    union { bf16_t h[4]; uint2 u; } pk;
    pk.h[0] = (bf16_t)((v.x - mean) * rstd * gv.x + bv.x);
    pk.h[1] = (bf16_t)((v.y - mean) * rstd * gv.y + bv.y);
    pk.h[2] = (bf16_t)((v.z - mean) * rstd * gv.z + bv.z);
    pk.h[3] = (bf16_t)((v.w - mean) * rstd * gv.w + bv.w);
    *(uint2*)(outp + row * 1024 + t * 4) = pk.u;
}

// ---------------- final layernorm (bf16 in + f32 res -> f32 out, res may == out) ----------------
__global__ __launch_bounds__(256)
void ln3_kernel(const bf16_t* __restrict__ in, const float* __restrict__ g,
                const float* __restrict__ be, float* outp, const float* res)
{
    const long row = blockIdx.x;
    const int t = threadIdx.x;
    union { uint2 u; bf16_t h[4]; } pk;
    pk.u = *(const uint2*)(in + row * 1024 + t * 4);
    float v0 = (float)pk.h[0], v1 = (float)pk.h[1], v2 = (float)pk.h[2], v3 = (float)pk.h[3];
    float s  = v0 + v1 + v2 + v3;
    float sq = v0 * v0 + v1 * v1 + v2 * v2 + v3 * v3;
#pragma unroll
    for (int off = 1; off < 64; off <<= 1) {
        s  += __shfl_xor(s, off);
        sq += __shfl_xor(sq, off);
    }
    __shared__ float red[8];
    if ((t & 63) == 0) { red[(t >> 6) * 2] = s; red[(t >> 6) * 2 + 1] = sq; }
    __syncthreads();
    s  = red[0] + red[2] + red[4] + red[6];
    sq = red[1] + red[3] + red[5] + red[7];
    float mean = s * 0.0009765625f;
    float var  = sq * 0.0009765625f - mean * mean;
    float rstd = rsqrtf(var + LN_EPS);
    float4 gv = ((const float4*)g)[t];
    float4 bv = ((const float4*)be)[t];
    float4 rv = ((const float4*)(res + row * 1024))[t];
    float4 ov;
    ov.x = rv.x + (v0 - mean) * rstd * gv.x + bv.x;
    ov.y = rv.y + (v1 - mean) * rstd * gv.y + bv.y;
    ov.z = rv.z + (v2 - mean) * rstd * gv.z + bv.z;
    ov.w = rv.w + (v3 - mean) * rstd * gv.w + bv.w;
    ((float4*)outp)[row * 256 + t] = ov;
}

// ---------------- GEMM: C[M,N] = A[M,K] * Bt[N,K]^T ----------------
// MODE 0: out bf16 = acc
// MODE 1: out f32  = acc + bias[col] + addf32[row,col]
// MODE 2: out bf16 = relu(acc + bias[col])
// MODE 3: out bf16 = acc + bias[col] + (float)addbf16[row,col]   (outp may == addp, elementwise)
template<int MODE>
__global__ __launch_bounds__(256)
void gemm_bt(const bf16_t* __restrict__ A, const bf16_t* __restrict__ Bt,
             void* outp, const float* __restrict__ bias,
             const void* addp, int M, int N, int K)
{
    __shared__ __attribute__((aligned(16))) bf16_t As[128 * 64];
    __shared__ __attribute__((aligned(16))) bf16_t Bs[128 * 64];
    const int tid  = threadIdx.x;
    const int w    = tid >> 6, lane = tid & 63;
    const int l16  = lane & 15, lg = lane >> 4;
    const int wm   = w >> 1, wn = w & 1;
    const long m0  = (long)blockIdx.x * 128;
    const long n0  = (long)blockIdx.y * 128;
    const int srow = lane >> 3;            // 0..7
    const int scol = (lane & 7) * 8;       // element offset in a 64-wide row

    f32x4 acc[4][4] = {};
    const int nkt = K >> 6;
    const bf16_t* Abase = A  + (m0 + 32 * w + srow) * (long)K + scol;
    const bf16_t* Bbase = Bt + (n0 + 32 * w + srow) * (long)K + scol;

    for (int kt = 0; kt < nkt; ++kt) {
        __syncthreads();
#pragma unroll
        for (int i = 0; i < 4; ++i) {
            gload_lds16(Abase + (long)8 * i * K + kt * 64, &As[(32 * w + 8 * i) * 64]);
            gload_lds16(Bbase + (long)8 * i * K + kt * 64, &Bs[(32 * w + 8 * i) * 64]);
        }
        asm volatile("s_waitcnt vmcnt(0)" ::: "memory");
        __syncthreads();
#pragma unroll
        for (int kk = 0; kk < 2; ++kk) {
            bf16x8 a[4], b[4];
#pragma unroll
            for (int f = 0; f < 4; ++f) {
                a[f] = *(const bf16x8*)&As[(wm * 64 + f * 16 + l16) * 64 + kk * 32 + lg * 8];
                b[f] = *(const bf16x8*)&Bs[(wn * 64 + f * 16 + l16) * 64 + kk * 32 + lg * 8];
            }
#pragma unroll
            for (int fm = 0; fm < 4; ++fm)
#pragma unroll
                for (int fn = 0; fn < 4; ++fn)
                    acc[fm][fn] = __builtin_amdgcn_mfma_f32_16x16x32_bf16(
                        a[fm], b[fn], acc[fm][fn], 0, 0, 0);
        }
    }

#pragma unroll
    for (int fm = 0; fm < 4; ++fm) {
#pragma unroll
        for (int fn = 0; fn < 4; ++fn) {
            const long gcol = n0 + wn * 64 + fn * 16 + l16;
            float bv = 0.f;
            if (MODE != 0) bv = bias[gcol];
#pragma unroll
            for (int e = 0; e < 4; ++e) {
                const long grow = m0 + wm * 64 + fm * 16 + lg * 4 + e;
                float v = acc[fm][fn][e];
                if (MODE == 0) {
                    ((bf16_t*)outp)[grow * N + gcol] = (bf16_t)v;
                } else if (MODE == 1) {
                    v += bv + ((const float*)addp)[grow * N + gcol];
                    ((float*)outp)[grow * N + gcol] = v;
                } else if (MODE == 2) {
                    v += bv; v = v > 0.f ? v : 0.f;
                    ((bf16_t*)outp)[grow * N + gcol] = (bf16_t)v;
                } else {
                    v += bv + (float)((const bf16_t*)addp)[grow * N + gcol];
                    ((bf16_t*)outp)[grow * N + gcol] = (bf16_t)v;
                }
            }
        }
    }
}

// ---------------- fused causal attention ----------------
// qkv: [B*T, 3072] bf16 (q | k | v each 1024 cols, col = h*64+d)
// out: [B*T, 1024] bf16 (col = h*64+d)
// 1 block per (b,h); 4 waves; wave w owns Q rows [64w, 64w+64)
__global__ __launch_bounds__(256)
void attn_kernel(const bf16_t* __restrict__ qkv, bf16_t* __restrict__ outp)
{
    __shared__ __attribute__((aligned(16))) bf16_t Kt[64 * 72];
    __shared__ __attribute__((aligned(16))) bf16_t Vt[64 * 72];
    __shared__ __attribute__((aligned(16))) bf16_t Ps[4][16 * 72];

    const int tid = threadIdx.x, w = tid >> 6, lane = tid & 63;
    const int l16 = lane & 15, lg = lane >> 4;
    const int b = blockIdx.x >> 4, hh = blockIdx.x & 15;
    const bf16_t* pq = qkv + (long)(b * 256) * 3072 + hh * 64;

    bf16x8 qf[4][2];
#pragma unroll
    for (int fm = 0; fm < 4; ++fm)
#pragma unroll
        for (int kk = 0; kk < 2; ++kk)
            qf[fm][kk] = *(const bf16x8*)(pq + (long)(w * 64 + fm * 16 + l16) * 3072
                                          + kk * 32 + lg * 8);

    f32x4 o[4][4] = {};
    float mrun[4][4], lrun[4][4];
#pragma unroll
    for (int i = 0; i < 4; ++i)
#pragma unroll
        for (int j = 0; j < 4; ++j) { mrun[i][j] = -__builtin_inff(); lrun[i][j] = 0.f; }

    for (int st = 0; st < 4; ++st) {
        __syncthreads();
        // stage K tile [64 x 64] and V^T tile [64 x 64] for s in [64*st, 64*st+64)
#pragma unroll
        for (int i = 0; i < 2; ++i) {
            int idx = i * 256 + tid;            // 0..511
            int sr = idx >> 3, sc = (idx & 7) * 8;
            const bf16_t* src = pq + (long)(st * 64 + sr) * 3072;
            bf16x8 kv = *(const bf16x8*)(src + 1024 + sc);
            *(bf16x8*)&Kt[sr * 72 + sc] = kv;
            bf16x8 vv = *(const bf16x8*)(src + 2048 + sc);
#pragma unroll
            for (int e = 0; e < 8; ++e) Vt[(sc + e) * 72 + sr] = vv[e];
        }
        __syncthreads();
        if (st > w) continue;

        // S = Q K^T
        f32x4 s[4][4] = {};
#pragma unroll
        for (int ks = 0; ks < 2; ++ks) {
            bf16x8 kb[4];
#pragma unroll
            for (int fs = 0; fs < 4; ++fs)
                kb[fs] = *(const bf16x8*)&Kt[(fs * 16 + l16) * 72 + ks * 32 + lg * 8];
#pragma unroll
            for (int fm = 0; fm < 4; ++fm)
#pragma unroll
                for (int fs = 0; fs < 4; ++fs)
                    s[fm][fs] = __builtin_amdgcn_mfma_f32_16x16x32_bf16(
                        qf[fm][ks], kb[fs], s[fm][fs], 0, 0, 0);
        }

#pragma unroll
        for (int fm = 0; fm < 4; ++fm) {
            // scale + causal mask
#pragma unroll
            for (int fs = 0; fs < 4; ++fs)
#pragma unroll
                for (int e = 0; e < 4; ++e) {
                    float v = s[fm][fs][e] * 0.03125f;   // C^-0.5, C=1024
                    if (st == w && (fs * 16 + l16) > (fm * 16 + lg * 4 + e))
                        v = -__builtin_inff();
                    s[fm][fs][e] = v;
                }
            // online softmax per row (row owned by 16 lanes sharing lg)
#pragma unroll
            for (int e = 0; e < 4; ++e) {
                float pm = fmaxf(fmaxf(s[fm][0][e], s[fm][1][e]),
                                 fmaxf(s[fm][2][e], s[fm][3][e]));
#pragma unroll
                for (int off = 1; off < 16; off <<= 1) pm = fmaxf(pm, __shfl_xor(pm, off));
                float mnew  = fmaxf(mrun[fm][e], pm);
                float alpha = __expf(mrun[fm][e] - mnew);
                float rs = 0.f;
#pragma unroll
                for (int fs = 0; fs < 4; ++fs) {
                    float p = __expf(s[fm][fs][e] - mnew);
                    s[fm][fs][e] = p;
                    rs += p;
                }
#pragma unroll
                for (int off = 1; off < 16; off <<= 1) rs += __shfl_xor(rs, off);
                lrun[fm][e] = lrun[fm][e] * alpha + rs;
                mrun[fm][e] = mnew;
#pragma unroll
                for (int fd = 0; fd < 4; ++fd) o[fm][fd][e] *= alpha;
            }
            // P -> LDS (bf16), then PV MFMA
#pragma unroll
            for (int fs = 0; fs < 4; ++fs)
#pragma unroll
                for (int e = 0; e < 4; ++e)
                    Ps[w][(lg * 4 + e) * 72 + fs * 16 + l16] = (bf16_t)s[fm][fs][e];
            bf16x8 ap0 = *(const bf16x8*)&Ps[w][l16 * 72 + lg * 8];
            bf16x8 ap1 = *(const bf16x8*)&Ps[w][l16 * 72 + 32 + lg * 8];
#pragma unroll
            for (int fd = 0; fd < 4; ++fd) {
                bf16x8 vb0 = *(const bf16x8*)&Vt[(fd * 16 + l16) * 72 + lg * 8];
                bf16x8 vb1 = *(const bf16x8*)&Vt[(fd * 16 + l16) * 72 + 32 + lg * 8];
                o[fm][fd] = __builtin_amdgcn_mfma_f32_16x16x32_bf16(ap0, vb0, o[fm][fd], 0, 0, 0);
                o[fm][fd] = __builtin_amdgcn_mfma_f32_16x16x32_bf16(ap1, vb1, o[fm][fd], 0, 0, 0);
            }
        }
    }

#pragma unroll
    for (int fm = 0; fm < 4; ++fm)
#pragma unroll
        for (int e = 0; e < 4; ++e) {
            float inv = 1.f / lrun[fm][e];
            long row = (long)b * 256 + w * 64 + fm * 16 + lg * 4 + e;
#pragma unroll
            for (int fd = 0; fd < 4; ++fd)
                outp[row * 1024 + hh * 64 + fd * 16 + l16] =
                    (bf16_t)(o[fm][fd][e] * inv);
        }
}

// ---------------- launch ----------------
extern "C" void kernel_launch(void* const* d_in, const int* in_sizes, int n_in,
                              void* d_out, int out_size, void* d_ws, size_t ws_size,
                              hipStream_t stream)
{
    (void)in_sizes; (void)n_in; (void)out_size; (void)ws_size;
    const float* x      = (const float*)d_in[0];
    const float* wq     = (const float*)d_in[1];
    const float* wk     = (const float*)d_in[2];
    const float* wv     = (const float*)d_in[3];
    const float* w_proj = (const float*)d_in[4];
    const float* b_proj = (const float*)d_in[5];
    const float* w1     = (const float*)d_in[6];
    const float* b1     = (const float*)d_in[7];
    const float* w2     = (const float*)d_in[8];
    const float* b2     = (const float*)d_in[9];
    const float* g1  = (const float*)d_in[10]; const float* be1 = (const float*)d_in[11];
    const float* g2  = (const float*)d_in[12]; const float* be2 = (const float*)d_in[13];
    const float* g3  = (const float*)d_in[14]; const float* be3 = (const float*)d_in[15];

    char* ws = (char*)d_ws;
    // compact layout, total 192,937,984 bytes (~184 MiB):
    bf16_t* wqkv  = (bf16_t*)(ws + 0);           //  6,291,456
    bf16_t* wproj = (bf16_t*)(ws + 6291456);     //  2,097,152
    bf16_t* w1t   = (bf16_t*)(ws + 8388608);     //  8,388,608
    bf16_t* w2t   = (bf16_t*)(ws + 16777216);    //  8,388,608
    bf16_t* h     = (bf16_t*)(ws + 25165824);    // 33,554,432 (LN1 out; later attn out; later start of u)
    bf16_t* qkv   = (bf16_t*)(ws + 58720256);    // 100,663,296
    bf16_t* attn  = h;                           // reuses h after qkv GEMM
    bf16_t* u     = h;                           // 134,217,728 over dead h+qkv
    bf16_t* y     = (bf16_t*)(ws + 159383552);   // 33,554,432 (LN2 out; FFN2 writes in-place)
    float*  x2    = (float*)d_out;               // residual stream lives in d_out
    bf16_t* tbuf  = y;                           // FFN2 out, in-place over y

    const int M = 16384;

    pack_qkv_w<<<12288, 256, 0, stream>>>(wq, wk, wv, wqkv);
    transpose_w<<<4096, 256, 0, stream>>>(w_proj, wproj, 10, 10);
    transpose_w<<<16384, 256, 0, stream>>>(w1, w1t, 10, 12);
    transpose_w<<<16384, 256, 0, stream>>>(w2, w2t, 12, 10);

    // h = LN1(x)
    ln_fwd<<<M, 256, 0, stream>>>(x, g1, be1, h);
    // qkv = h @ Wqkv^T
    gemm_bt<0><<<dim3(128, 24), 256, 0, stream>>>(h, wqkv, qkv, nullptr, nullptr, M, 3072, 1024);
    // attention (writes over h region, disjoint from qkv)
    attn_kernel<<<1024, 256, 0, stream>>>(qkv, attn);
    // x2 = x + attn @ Wproj^T + b_proj   -> d_out (f32)
    gemm_bt<1><<<dim3(128, 8), 256, 0, stream>>>(attn, wproj, x2, b_proj, x, M, 1024, 1024);
    // y = LN2(x2)
    ln_fwd<<<M, 256, 0, stream>>>(x2, g2, be2, y);
    // u = relu(y @ W1^T + b1)   (overwrites dead attn+qkv region)
    gemm_bt<2><<<dim3(128, 32), 256, 0, stream>>>(y, w1t, u, b1, nullptr, M, 4096, 1024);
    // tbuf = y + (u @ W2^T + b2)  (bf16, in-place over y)
    gemm_bt<3><<<dim3(128, 8), 256, 0, stream>>>(u, w2t, tbuf, b2, y, M, 1024, 4096);
    // d_out = x2 + LN3(tbuf)   (in-place on d_out)
    ln3_kernel<<<M, 256, 0, stream>>>(tbuf, g3, be3, (float*)d_out, x2);
}

// Round 7
// 974.845 us; speedup vs baseline: 1.0028x; 1.0028x over previous
//
#include <hip/hip_runtime.h>

typedef __bf16 bf16_t;
typedef __bf16 bf16x8 __attribute__((ext_vector_type(8)));
typedef float f32x4 __attribute__((ext_vector_type(4)));

#define LN_EPS 1e-3f

__device__ __forceinline__ void gload_lds16(const void* g, void* l) {
    __builtin_amdgcn_global_load_lds(
        (__attribute__((address_space(1))) void*)(g),
        (__attribute__((address_space(3))) void*)(l), 16, 0, 0);
}

// ---------------- weight prep ----------------
// out[(sel*1024 + h*64 + d)*1024 + c] = w_sel[h][c][d]
__global__ void pack_qkv_w(const float* __restrict__ wq, const float* __restrict__ wk,
                           const float* __restrict__ wv, bf16_t* __restrict__ outp)
{
    int idx = blockIdx.x * 256 + threadIdx.x;       // 0 .. 3*1024*1024-1
    int c   = idx & 1023;
    int n   = idx >> 10;
    int sel = n >> 10;
    int hd  = n & 1023;
    const float* src = (sel == 0) ? wq : (sel == 1) ? wk : wv;
    outp[idx] = (bf16_t)src[((hd >> 6) * 1024 + c) * 64 + (hd & 63)];
}

// out[n*K + k] = in[k*N + n]   (K = 1<<lgK, N = 1<<lgN)
__global__ void transpose_w(const float* __restrict__ in, bf16_t* __restrict__ outp,
                            int lgK, int lgN)
{
    long idx = (long)blockIdx.x * 256 + threadIdx.x;
    long k = idx & ((1L << lgK) - 1);
    long n = idx >> lgK;
    outp[idx] = (bf16_t)in[n + (k << lgN)];
}

// ---------------- layernorm (f32 in -> bf16 LN out) ----------------
__global__ __launch_bounds__(256)
void ln_fwd(const float* __restrict__ in, const float* __restrict__ g,
            const float* __restrict__ be, bf16_t* __restrict__ outp)
{
    const long row = blockIdx.x;
    const int t = threadIdx.x;
    float4 v = ((const float4*)(in + row * 1024))[t];
    float s  = v.x + v.y + v.z + v.w;
    float sq = v.x * v.x + v.y * v.y + v.z * v.z + v.w * v.w;
#pragma unroll
    for (int off = 1; off < 64; off <<= 1) {
        s  += __shfl_xor(s, off);
        sq += __shfl_xor(sq, off);
    }
    __shared__ float red[8];
    if ((t & 63) == 0) { red[(t >> 6) * 2] = s; red[(t >> 6) * 2 + 1] = sq; }
    __syncthreads();
    s  = red[0] + red[2] + red[4] + red[6];
    sq = red[1] + red[3] + red[5] + red[7];
    float mean = s * 0.0009765625f;
    float var  = sq * 0.0009765625f - mean * mean;
    float rstd = rsqrtf(var + LN_EPS);
    float4 gv = ((const float4*)g)[t];
    float4 bv = ((const float4*)be)[t];
    union { bf16_t h[4]; uint2 u; } pk;
    pk.h[0] = (bf16_t)((v.x - mean) * rstd * gv.x + bv.x);
    pk.h[1] = (bf16_t)((v.y - mean) * rstd * gv.y + bv.y);
    pk.h[2] = (bf16_t)((v.z - mean) * rstd * gv.z + bv.z);
    pk.h[3] = (bf16_t)((v.w - mean) * rstd * gv.w + bv.w);
    *(uint2*)(outp + row * 1024 + t * 4) = pk.u;
}

// ---------------- final layernorm (bf16 in + f32 res -> f32 out, res may == out) ----------------
__global__ __launch_bounds__(256)
void ln3_kernel(const bf16_t* __restrict__ in, const float* __restrict__ g,
                const float* __restrict__ be, float* outp, const float* res)
{
    const long row = blockIdx.x;
    const int t = threadIdx.x;
    union { uint2 u; bf16_t h[4]; } pk;
    pk.u = *(const uint2*)(in + row * 1024 + t * 4);
    float v0 = (float)pk.h[0], v1 = (float)pk.h[1], v2 = (float)pk.h[2], v3 = (float)pk.h[3];
    float s  = v0 + v1 + v2 + v3;
    float sq = v0 * v0 + v1 * v1 + v2 * v2 + v3 * v3;
#pragma unroll
    for (int off = 1; off < 64; off <<= 1) {
        s  += __shfl_xor(s, off);
        sq += __shfl_xor(sq, off);
    }
    __shared__ float red[8];
    if ((t & 63) == 0) { red[(t >> 6) * 2] = s; red[(t >> 6) * 2 + 1] = sq; }
    __syncthreads();
    s  = red[0] + red[2] + red[4] + red[6];
    sq = red[1] + red[3] + red[5] + red[7];
    float mean = s * 0.0009765625f;
    float var  = sq * 0.0009765625f - mean * mean;
    float rstd = rsqrtf(var + LN_EPS);
    float4 gv = ((const float4*)g)[t];
    float4 bv = ((const float4*)be)[t];
    float4 rv = ((const float4*)(res + row * 1024))[t];
    float4 ov;
    ov.x = rv.x + (v0 - mean) * rstd * gv.x + bv.x;
    ov.y = rv.y + (v1 - mean) * rstd * gv.y + bv.y;
    ov.z = rv.z + (v2 - mean) * rstd * gv.z + bv.z;
    ov.w = rv.w + (v3 - mean) * rstd * gv.w + bv.w;
    ((float4*)outp)[row * 256 + t] = ov;
}

// ---------------- GEMM: C[M,N] = A[M,K] * Bt[N,K]^T ----------------
// 256x128 tile, BK=64, 512 threads (8 waves: wm=w>>1 in 0..3, wn=w&1).
// 3-deep LDS pipeline: iter t reads buf[t%3], stages tile t+2 into buf[(t+2)%3].
// Counted s_waitcnt vmcnt(6) before raw s_barrier (6 loads/thread/tile in flight).
// XOR swizzle: LDS[r][slot] holds global slot (slot ^ (r&7)) (16B granularity);
// inverse swizzle applied on per-lane global source (global_load_lds dest is linear).
// MODE 0: out bf16 = acc
// MODE 1: out f32  = acc + bias[col] + addf32[row,col]
// MODE 2: out bf16 = relu(acc + bias[col])
// MODE 3: out bf16 = acc + bias[col] + (float)addbf16[row,col]   (outp may == addp, elementwise)
template<int MODE>
__global__ __launch_bounds__(512, 2)
void gemm_bt(const bf16_t* __restrict__ A, const bf16_t* __restrict__ Bt,
             void* outp, const float* __restrict__ bias,
             const void* addp, int M, int N, int K)
{
    __shared__ __attribute__((aligned(16))) bf16_t As[3][256 * 64];
    __shared__ __attribute__((aligned(16))) bf16_t Bs[3][128 * 64];

    const int tid  = threadIdx.x;
    const int w    = tid >> 6, lane = tid & 63;
    const int l16  = lane & 15, lg = lane >> 4;
    const int wm   = w >> 1, wn = w & 1;
    const long m0  = (long)blockIdx.x * 256;
    const long n0  = (long)blockIdx.y * 128;
    const int nkt  = K >> 6;

    const int srow = lane >> 3;          // 0..7 within the wave's 8-row stripe
    const int sslot = lane & 7;          // 16B slot within 128B row

    f32x4 acc[4][4] = {};

    // ---- staging: 6 x global_load_lds per thread per K-tile ----
    auto STAGE = [&](int kt, int sb) {
#pragma unroll
        for (int i = 0; i < 4; ++i) {
            int r  = i * 64 + w * 8 + srow;               // tile row 0..255
            int ss = sslot ^ (r & 7);                     // inverse swizzle on source
            gload_lds16(A + (m0 + r) * (long)K + (long)kt * 64 + ss * 8,
                        &As[sb][(i * 64 + w * 8) * 64]);
        }
#pragma unroll
        for (int i = 0; i < 2; ++i) {
            int r  = i * 64 + w * 8 + srow;               // tile row 0..127
            int ss = sslot ^ (r & 7);
            gload_lds16(Bt + (n0 + r) * (long)K + (long)kt * 64 + ss * 8,
                        &Bs[sb][(i * 64 + w * 8) * 64]);
        }
    };

    // prologue: stage tiles 0 and 1
    STAGE(0, 0);
    STAGE(nkt > 1 ? 1 : 0, 1);
    if (nkt > 1) { asm volatile("s_waitcnt vmcnt(6)" ::: "memory"); }
    else         { asm volatile("s_waitcnt vmcnt(0)" ::: "memory"); }
    __builtin_amdgcn_s_barrier();
    __builtin_amdgcn_sched_barrier(0);

    int buf = 0, sbuf = 2;
    for (int t = 0; t < nkt; ++t) {
        const bool pf = (t + 2 < nkt);
        if (pf) STAGE(t + 2, sbuf);

        // A fragments for this K-tile (reused by both MFMA clusters)
        bf16x8 a[4][2];
#pragma unroll
        for (int fm = 0; fm < 4; ++fm)
#pragma unroll
            for (int kk = 0; kk < 2; ++kk) {
                int r  = wm * 64 + fm * 16 + l16;
                int ss = (kk * 4 + lg) ^ (r & 7);
                a[fm][kk] = *(const bf16x8*)&As[buf][r * 64 + ss * 8];
            }
        // B fragments fn=0..1, MFMA cluster 0
        bf16x8 b0[2][2];
#pragma unroll
        for (int fn = 0; fn < 2; ++fn)
#pragma unroll
            for (int kk = 0; kk < 2; ++kk) {
                int r  = wn * 64 + fn * 16 + l16;
                int ss = (kk * 4 + lg) ^ (r & 7);
                b0[fn][kk] = *(const bf16x8*)&Bs[buf][r * 64 + ss * 8];
            }
        __builtin_amdgcn_s_setprio(1);
#pragma unroll
        for (int fm = 0; fm < 4; ++fm)
#pragma unroll
            for (int fn = 0; fn < 2; ++fn)
#pragma unroll
                for (int kk = 0; kk < 2; ++kk)
                    acc[fm][fn] = __builtin_amdgcn_mfma_f32_16x16x32_bf16(
                        a[fm][kk], b0[fn][kk], acc[fm][fn], 0, 0, 0);
        __builtin_amdgcn_s_setprio(0);

        // B fragments fn=2..3, MFMA cluster 1
        bf16x8 b1[2][2];
#pragma unroll
        for (int fn = 0; fn < 2; ++fn)
#pragma unroll
            for (int kk = 0; kk < 2; ++kk) {
                int r  = wn * 64 + (fn + 2) * 16 + l16;
                int ss = (kk * 4 + lg) ^ (r & 7);
                b1[fn][kk] = *(const bf16x8*)&Bs[buf][r * 64 + ss * 8];
            }
        __builtin_amdgcn_s_setprio(1);
#pragma unroll
        for (int fm = 0; fm < 4; ++fm)
#pragma unroll
            for (int fn = 0; fn < 2; ++fn)
#pragma unroll
                for (int kk = 0; kk < 2; ++kk)
                    acc[fm][fn + 2] = __builtin_amdgcn_mfma_f32_16x16x32_bf16(
                        a[fm][kk], b1[fn][kk], acc[fm][fn + 2], 0, 0, 0);
        __builtin_amdgcn_s_setprio(0);

        // tile t+1 must have landed; keep tile t+2's loads in flight
        if (pf) { asm volatile("s_waitcnt vmcnt(6)" ::: "memory"); }
        else    { asm volatile("s_waitcnt vmcnt(0)" ::: "memory"); }
        __builtin_amdgcn_s_barrier();
        __builtin_amdgcn_sched_barrier(0);

        buf  = (buf == 2)  ? 0 : buf + 1;
        sbuf = (sbuf == 2) ? 0 : sbuf + 1;
    }

    // ---- epilogue ----
#pragma unroll
    for (int fm = 0; fm < 4; ++fm) {
#pragma unroll
        for (int fn = 0; fn < 4; ++fn) {
            const long gcol = n0 + wn * 64 + fn * 16 + l16;
            float bv = 0.f;
            if (MODE != 0) bv = bias[gcol];
#pragma unroll
            for (int e = 0; e < 4; ++e) {
                const long grow = m0 + wm * 64 + fm * 16 + lg * 4 + e;
                float v = acc[fm][fn][e];
                if (MODE == 0) {
                    ((bf16_t*)outp)[grow * N + gcol] = (bf16_t)v;
                } else if (MODE == 1) {
                    v += bv + ((const float*)addp)[grow * N + gcol];
                    ((float*)outp)[grow * N + gcol] = v;
                } else if (MODE == 2) {
                    v += bv; v = v > 0.f ? v : 0.f;
                    ((bf16_t*)outp)[grow * N + gcol] = (bf16_t)v;
                } else {
                    v += bv + (float)((const bf16_t*)addp)[grow * N + gcol];
                    ((bf16_t*)outp)[grow * N + gcol] = (bf16_t)v;
                }
            }
        }
    }
}

// ---------------- fused causal attention ----------------
// qkv: [B*T, 3072] bf16 (q | k | v each 1024 cols, col = h*64+d)
// out: [B*T, 1024] bf16 (col = h*64+d)
// 1 block per (b,h); 4 waves; wave w owns Q rows [64w, 64w+64)
__global__ __launch_bounds__(256)
void attn_kernel(const bf16_t* __restrict__ qkv, bf16_t* __restrict__ outp)
{
    __shared__ __attribute__((aligned(16))) bf16_t Kt[64 * 72];
    __shared__ __attribute__((aligned(16))) bf16_t Vt[64 * 72];
    __shared__ __attribute__((aligned(16))) bf16_t Ps[4][16 * 72];

    const int tid = threadIdx.x, w = tid >> 6, lane = tid & 63;
    const int l16 = lane & 15, lg = lane >> 4;
    const int b = blockIdx.x >> 4, hh = blockIdx.x & 15;
    const bf16_t* pq = qkv + (long)(b * 256) * 3072 + hh * 64;

    bf16x8 qf[4][2];
#pragma unroll
    for (int fm = 0; fm < 4; ++fm)
#pragma unroll
        for (int kk = 0; kk < 2; ++kk)
            qf[fm][kk] = *(const bf16x8*)(pq + (long)(w * 64 + fm * 16 + l16) * 3072
                                          + kk * 32 + lg * 8);

    f32x4 o[4][4] = {};
    float mrun[4][4], lrun[4][4];
#pragma unroll
    for (int i = 0; i < 4; ++i)
#pragma unroll
        for (int j = 0; j < 4; ++j) { mrun[i][j] = -__builtin_inff(); lrun[i][j] = 0.f; }

    for (int st = 0; st < 4; ++st) {
        __syncthreads();
        // stage K tile [64 x 64] and V^T tile [64 x 64] for s in [64*st, 64*st+64)
#pragma unroll
        for (int i = 0; i < 2; ++i) {
            int idx = i * 256 + tid;            // 0..511
            int sr = idx >> 3, sc = (idx & 7) * 8;
            const bf16_t* src = pq + (long)(st * 64 + sr) * 3072;
            bf16x8 kv = *(const bf16x8*)(src + 1024 + sc);
            *(bf16x8*)&Kt[sr * 72 + sc] = kv;
            bf16x8 vv = *(const bf16x8*)(src + 2048 + sc);
#pragma unroll
            for (int e = 0; e < 8; ++e) Vt[(sc + e) * 72 + sr] = vv[e];
        }
        __syncthreads();
        if (st > w) continue;

        // S = Q K^T
        f32x4 s[4][4] = {};
#pragma unroll
        for (int ks = 0; ks < 2; ++ks) {
            bf16x8 kb[4];
#pragma unroll
            for (int fs = 0; fs < 4; ++fs)
                kb[fs] = *(const bf16x8*)&Kt[(fs * 16 + l16) * 72 + ks * 32 + lg * 8];
#pragma unroll
            for (int fm = 0; fm < 4; ++fm)
#pragma unroll
                for (int fs = 0; fs < 4; ++fs)
                    s[fm][fs] = __builtin_amdgcn_mfma_f32_16x16x32_bf16(
                        qf[fm][ks], kb[fs], s[fm][fs], 0, 0, 0);
        }

#pragma unroll
        for (int fm = 0; fm < 4; ++fm) {
            // scale + causal mask
#pragma unroll
            for (int fs = 0; fs < 4; ++fs)
#pragma unroll
                for (int e = 0; e < 4; ++e) {
                    float v = s[fm][fs][e] * 0.03125f;   // C^-0.5, C=1024
                    if (st == w && (fs * 16 + l16) > (fm * 16 + lg * 4 + e))
                        v = -__builtin_inff();
                    s[fm][fs][e] = v;
                }
            // online softmax per row (row owned by 16 lanes sharing lg)
#pragma unroll
            for (int e = 0; e < 4; ++e) {
                float pm = fmaxf(fmaxf(s[fm][0][e], s[fm][1][e]),
                                 fmaxf(s[fm][2][e], s[fm][3][e]));
#pragma unroll
                for (int off = 1; off < 16; off <<= 1) pm = fmaxf(pm, __shfl_xor(pm, off));
                float mnew  = fmaxf(mrun[fm][e], pm);
                float alpha = __expf(mrun[fm][e] - mnew);
                float rs = 0.f;
#pragma unroll
                for (int fs = 0; fs < 4; ++fs) {
                    float p = __expf(s[fm][fs][e] - mnew);
                    s[fm][fs][e] = p;
                    rs += p;
                }
#pragma unroll
                for (int off = 1; off < 16; off <<= 1) rs += __shfl_xor(rs, off);
                lrun[fm][e] = lrun[fm][e] * alpha + rs;
                mrun[fm][e] = mnew;
#pragma unroll
                for (int fd = 0; fd < 4; ++fd) o[fm][fd][e] *= alpha;
            }
            // P -> LDS (bf16), then PV MFMA
#pragma unroll
            for (int fs = 0; fs < 4; ++fs)
#pragma unroll
                for (int e = 0; e < 4; ++e)
                    Ps[w][(lg * 4 + e) * 72 + fs * 16 + l16] = (bf16_t)s[fm][fs][e];
            bf16x8 ap0 = *(const bf16x8*)&Ps[w][l16 * 72 + lg * 8];
            bf16x8 ap1 = *(const bf16x8*)&Ps[w][l16 * 72 + 32 + lg * 8];
#pragma unroll
            for (int fd = 0; fd < 4; ++fd) {
                bf16x8 vb0 = *(const bf16x8*)&Vt[(fd * 16 + l16) * 72 + lg * 8];
                bf16x8 vb1 = *(const bf16x8*)&Vt[(fd * 16 + l16) * 72 + 32 + lg * 8];
                o[fm][fd] = __builtin_amdgcn_mfma_f32_16x16x32_bf16(ap0, vb0, o[fm][fd], 0, 0, 0);
                o[fm][fd] = __builtin_amdgcn_mfma_f32_16x16x32_bf16(ap1, vb1, o[fm][fd], 0, 0, 0);
            }
        }
    }

#pragma unroll
    for (int fm = 0; fm < 4; ++fm)
#pragma unroll
        for (int e = 0; e < 4; ++e) {
            float inv = 1.f / lrun[fm][e];
            long row = (long)b * 256 + w * 64 + fm * 16 + lg * 4 + e;
#pragma unroll
            for (int fd = 0; fd < 4; ++fd)
                outp[row * 1024 + hh * 64 + fd * 16 + l16] =
                    (bf16_t)(o[fm][fd][e] * inv);
        }
}

// ---------------- launch ----------------
extern "C" void kernel_launch(void* const* d_in, const int* in_sizes, int n_in,
                              void* d_out, int out_size, void* d_ws, size_t ws_size,
                              hipStream_t stream)
{
    (void)in_sizes; (void)n_in; (void)out_size; (void)ws_size;
    const float* x      = (const float*)d_in[0];
    const float* wq     = (const float*)d_in[1];
    const float* wk     = (const float*)d_in[2];
    const float* wv     = (const float*)d_in[3];
    const float* w_proj = (const float*)d_in[4];
    const float* b_proj = (const float*)d_in[5];
    const float* w1     = (const float*)d_in[6];
    const float* b1     = (const float*)d_in[7];
    const float* w2     = (const float*)d_in[8];
    const float* b2     = (const float*)d_in[9];
    const float* g1  = (const float*)d_in[10]; const float* be1 = (const float*)d_in[11];
    const float* g2  = (const float*)d_in[12]; const float* be2 = (const float*)d_in[13];
    const float* g3  = (const float*)d_in[14]; const float* be3 = (const float*)d_in[15];

    char* ws = (char*)d_ws;
    // compact layout, total 192,937,984 bytes (~184 MiB):
    bf16_t* wqkv  = (bf16_t*)(ws + 0);           //  6,291,456
    bf16_t* wproj = (bf16_t*)(ws + 6291456);     //  2,097,152
    bf16_t* w1t   = (bf16_t*)(ws + 8388608);     //  8,388,608
    bf16_t* w2t   = (bf16_t*)(ws + 16777216);    //  8,388,608
    bf16_t* h     = (bf16_t*)(ws + 25165824);    // 33,554,432 (LN1 out; later attn out; later start of u)
    bf16_t* qkv   = (bf16_t*)(ws + 58720256);    // 100,663,296
    bf16_t* attn  = h;                           // reuses h after qkv GEMM
    bf16_t* u     = h;                           // 134,217,728 over dead h+qkv
    bf16_t* y     = (bf16_t*)(ws + 159383552);   // 33,554,432 (LN2 out; FFN2 writes in-place)
    float*  x2    = (float*)d_out;               // residual stream lives in d_out
    bf16_t* tbuf  = y;                           // FFN2 out, in-place over y

    const int M = 16384;

    pack_qkv_w<<<12288, 256, 0, stream>>>(wq, wk, wv, wqkv);
    transpose_w<<<4096, 256, 0, stream>>>(w_proj, wproj, 10, 10);
    transpose_w<<<16384, 256, 0, stream>>>(w1, w1t, 10, 12);
    transpose_w<<<16384, 256, 0, stream>>>(w2, w2t, 12, 10);

    // h = LN1(x)
    ln_fwd<<<M, 256, 0, stream>>>(x, g1, be1, h);
    // qkv = h @ Wqkv^T
    gemm_bt<0><<<dim3(64, 24), 512, 0, stream>>>(h, wqkv, qkv, nullptr, nullptr, M, 3072, 1024);
    // attention (writes over h region, disjoint from qkv)
    attn_kernel<<<1024, 256, 0, stream>>>(qkv, attn);
    // x2 = x + attn @ Wproj^T + b_proj   -> d_out (f32)
    gemm_bt<1><<<dim3(64, 8), 512, 0, stream>>>(attn, wproj, x2, b_proj, x, M, 1024, 1024);
    // y = LN2(x2)
    ln_fwd<<<M, 256, 0, stream>>>(x2, g2, be2, y);
    // u = relu(y @ W1^T + b1)   (overwrites dead attn+qkv region)
    gemm_bt<2><<<dim3(64, 32), 512, 0, stream>>>(y, w1t, u, b1, nullptr, M, 4096, 1024);
    // tbuf = y + (u @ W2^T + b2)  (bf16, in-place over y)
    gemm_bt<3><<<dim3(64, 8), 512, 0, stream>>>(u, w2t, tbuf, b2, y, M, 1024, 4096);
    // d_out = x2 + LN3(tbuf)   (in-place on d_out)
    ln3_kernel<<<M, 256, 0, stream>>>(tbuf, g3, be3, (float*)d_out, x2);
}

// Round 8
// 765.153 us; speedup vs baseline: 1.2776x; 1.2741x over previous
//
#include <hip/hip_runtime.h>

typedef __bf16 bf16_t;
typedef __bf16 bf16x8 __attribute__((ext_vector_type(8)));
typedef float f32x4 __attribute__((ext_vector_type(4)));

#define LN_EPS 1e-3f

__device__ __forceinline__ void gload_lds16(const void* g, void* l) {
    __builtin_amdgcn_global_load_lds(
        (__attribute__((address_space(1))) void*)(g),
        (__attribute__((address_space(3))) void*)(l), 16, 0, 0);
}

// ---------------- weight prep ----------------
__global__ void pack_qkv_w(const float* __restrict__ wq, const float* __restrict__ wk,
                           const float* __restrict__ wv, bf16_t* __restrict__ outp)
{
    int idx = blockIdx.x * 256 + threadIdx.x;
    int c   = idx & 1023;
    int n   = idx >> 10;
    int sel = n >> 10;
    int hd  = n & 1023;
    const float* src = (sel == 0) ? wq : (sel == 1) ? wk : wv;
    outp[idx] = (bf16_t)src[((hd >> 6) * 1024 + c) * 64 + (hd & 63)];
}

__global__ void transpose_w(const float* __restrict__ in, bf16_t* __restrict__ outp,
                            int lgK, int lgN)
{
    long idx = (long)blockIdx.x * 256 + threadIdx.x;
    long k = idx & ((1L << lgK) - 1);
    long n = idx >> lgK;
    outp[idx] = (bf16_t)in[n + (k << lgN)];
}

// ---------------- layernorm (f32 in -> bf16 LN out) ----------------
__global__ __launch_bounds__(256)
void ln_fwd(const float* __restrict__ in, const float* __restrict__ g,
            const float* __restrict__ be, bf16_t* __restrict__ outp)
{
    const long row = blockIdx.x;
    const int t = threadIdx.x;
    float4 v = ((const float4*)(in + row * 1024))[t];
    float s  = v.x + v.y + v.z + v.w;
    float sq = v.x * v.x + v.y * v.y + v.z * v.z + v.w * v.w;
#pragma unroll
    for (int off = 1; off < 64; off <<= 1) {
        s  += __shfl_xor(s, off);
        sq += __shfl_xor(sq, off);
    }
    __shared__ float red[8];
    if ((t & 63) == 0) { red[(t >> 6) * 2] = s; red[(t >> 6) * 2 + 1] = sq; }
    __syncthreads();
    s  = red[0] + red[2] + red[4] + red[6];
    sq = red[1] + red[3] + red[5] + red[7];
    float mean = s * 0.0009765625f;
    float var  = sq * 0.0009765625f - mean * mean;
    float rstd = rsqrtf(var + LN_EPS);
    float4 gv = ((const float4*)g)[t];
    float4 bv = ((const float4*)be)[t];
    union { bf16_t h[4]; uint2 u; } pk;
    pk.h[0] = (bf16_t)((v.x - mean) * rstd * gv.x + bv.x);
    pk.h[1] = (bf16_t)((v.y - mean) * rstd * gv.y + bv.y);
    pk.h[2] = (bf16_t)((v.z - mean) * rstd * gv.z + bv.z);
    pk.h[3] = (bf16_t)((v.w - mean) * rstd * gv.w + bv.w);
    *(uint2*)(outp + row * 1024 + t * 4) = pk.u;
}

// ---------------- final layernorm (bf16 in + f32 res -> f32 out) ----------------
__global__ __launch_bounds__(256)
void ln3_kernel(const bf16_t* __restrict__ in, const float* __restrict__ g,
                const float* __restrict__ be, float* outp, const float* res)
{
    const long row = blockIdx.x;
    const int t = threadIdx.x;
    union { uint2 u; bf16_t h[4]; } pk;
    pk.u = *(const uint2*)(in + row * 1024 + t * 4);
    float v0 = (float)pk.h[0], v1 = (float)pk.h[1], v2 = (float)pk.h[2], v3 = (float)pk.h[3];
    float s  = v0 + v1 + v2 + v3;
    float sq = v0 * v0 + v1 * v1 + v2 * v2 + v3 * v3;
#pragma unroll
    for (int off = 1; off < 64; off <<= 1) {
        s  += __shfl_xor(s, off);
        sq += __shfl_xor(sq, off);
    }
    __shared__ float red[8];
    if ((t & 63) == 0) { red[(t >> 6) * 2] = s; red[(t >> 6) * 2 + 1] = sq; }
    __syncthreads();
    s  = red[0] + red[2] + red[4] + red[6];
    sq = red[1] + red[3] + red[5] + red[7];
    float mean = s * 0.0009765625f;
    float var  = sq * 0.0009765625f - mean * mean;
    float rstd = rsqrtf(var + LN_EPS);
    float4 gv = ((const float4*)g)[t];
    float4 bv = ((const float4*)be)[t];
    float4 rv = ((const float4*)(res + row * 1024))[t];
    float4 ov;
    ov.x = rv.x + (v0 - mean) * rstd * gv.x + bv.x;
    ov.y = rv.y + (v1 - mean) * rstd * gv.y + bv.y;
    ov.z = rv.z + (v2 - mean) * rstd * gv.z + bv.z;
    ov.w = rv.w + (v3 - mean) * rstd * gv.w + bv.w;
    ((float4*)outp)[row * 256 + t] = ov;
}

// ---------------- GEMM: C[M,N] = A[M,K] * Bt[N,K]^T ----------------
// 256x256 tile, BK=64, 512 threads = 8 waves (wm = w>>2 in {0,1}, wn = w&3).
// 8-phase schedule (2 K-tiles per iteration), 2 LDS K-tile buffers (128 KB).
// Per K-tile, per wave: 4 quads of 16 MFMA; quad order (mh0,nh0)(mh0,nh1)(mh1,nh1)(mh1,nh0)
//   so A frags load at P1/P3 (P5/P7), B nh0 lives P1->P4, B nh1 lives P2->P3.
// Stage ledger (1 half-tile = 2 gload_lds/thread per phase):
//   P1: A-h1(c1)->As1 + B-h0(c1)->Bs1   (As1 last read prev-P7; Bs1 prev-P6)
//   P2: B-h1(c1)->Bs1
//   P3: B-h0(c2)->Bs0                    (Bs0 reads done after P2)
//   P4: B-h1(c2)->Bs0; vmcnt(4) [forces A(c1),B(c1) landed; leaves P3,P4]
//   P5: A-h0(c2)->As0                    (As0 reads done after P3)
//   P6: A-h1(c2)->As0
//   P7: (none)                           (As1 mh1 still being read here)
//   P8: A-h0(c3)->As1; vmcnt(2) [forces A(c2),B(c2) landed; leaves P8]
// Last iteration (pf=false): skip c2/c3 stages, P4 uses vmcnt(0).
// XOR swizzle (16B slots): LDS slot s holds global slot s^(row&7); inverse applied
// on per-lane global source (global_load_lds dest is linear). Conflict-free (r7: 0).
// MODE 0: out bf16 = acc
// MODE 1: out f32  = acc + bias[col] + addf32[row,col]
// MODE 2: out bf16 = relu(acc + bias[col])
// MODE 3: out bf16 = acc + bias[col] + (float)addbf16[row,col]  (outp may == addp)
template<int MODE>
__global__ __launch_bounds__(512, 2)
void gemm_bt(const bf16_t* __restrict__ Ap, const bf16_t* __restrict__ Bp,
             void* outp, const float* __restrict__ bias,
             const void* addp, int M, int N, int K)
{
    __shared__ __attribute__((aligned(16))) bf16_t As0[256 * 64];
    __shared__ __attribute__((aligned(16))) bf16_t As1[256 * 64];
    __shared__ __attribute__((aligned(16))) bf16_t Bs0[256 * 64];
    __shared__ __attribute__((aligned(16))) bf16_t Bs1[256 * 64];

    const int tid  = threadIdx.x;
    const int w    = tid >> 6, lane = tid & 63;
    const int l16  = lane & 15, lg = lane >> 4;
    const int wm   = w >> 2, wn = w & 3;
    const int srow = lane >> 3;          // 0..7
    const int sslot = lane & 7;          // 16B slot within 128B row

    // XCD-aware block swizzle (all grids have nwg % 8 == 0)
    const int gx  = gridDim.x;
    const int nwg = gx * gridDim.y;
    const int bid = blockIdx.y * gx + blockIdx.x;
    const int cpx = nwg >> 3;
    const int sid = (bid & 7) * cpx + (bid >> 3);
    const long m0 = (long)(sid % gx) * 256;
    const long n0 = (long)(sid / gx) * 256;
    const int nkt = K >> 6;

    f32x4 acc[8][4] = {};
    bf16x8 a[4][2], b0[2][2], b1[2][2];

    // stage one half-tile (h: rows h*128..h*128+127) of K-tile kt into dst
    auto STAGEH = [&](const bf16_t* src, long row0, int kt, bf16_t* dst, int h) {
#pragma unroll
        for (int i = 0; i < 2; ++i) {
            int r  = h * 128 + w * 16 + i * 8 + srow;
            int ss = sslot ^ (r & 7);
            gload_lds16(src + (row0 + r) * (long)K + (long)kt * 64 + ss * 8,
                        dst + (h * 128 + w * 16 + i * 8) * 64);
        }
    };

#define LDA_M(buf, mh) do {                                               \
    _Pragma("unroll") for (int j = 0; j < 4; ++j)                         \
    _Pragma("unroll") for (int kk = 0; kk < 2; ++kk) {                    \
        int r  = wm * 128 + (mh) * 64 + j * 16 + l16;                     \
        int ss = (kk * 4 + lg) ^ (r & 7);                                 \
        a[j][kk] = *(const bf16x8*)&buf[r * 64 + ss * 8];                 \
    } } while (0)

#define LDB_M(dst, buf, nh) do {                                          \
    _Pragma("unroll") for (int n = 0; n < 2; ++n)                         \
    _Pragma("unroll") for (int kk = 0; kk < 2; ++kk) {                    \
        int r  = wn * 64 + ((nh) * 2 + n) * 16 + l16;                     \
        int ss = (kk * 4 + lg) ^ (r & 7);                                 \
        dst[n][kk] = *(const bf16x8*)&buf[r * 64 + ss * 8];               \
    } } while (0)

#define MMA_M(bv, mh, nh) do {                                            \
    __builtin_amdgcn_s_setprio(1);                                        \
    _Pragma("unroll") for (int j = 0; j < 4; ++j)                         \
    _Pragma("unroll") for (int n = 0; n < 2; ++n)                         \
    _Pragma("unroll") for (int kk = 0; kk < 2; ++kk)                      \
        acc[(mh) * 4 + j][(nh) * 2 + n] =                                 \
            __builtin_amdgcn_mfma_f32_16x16x32_bf16(                      \
                a[j][kk], bv[n][kk], acc[(mh) * 4 + j][(nh) * 2 + n],     \
                0, 0, 0);                                                 \
    __builtin_amdgcn_s_setprio(0);                                        \
} while (0)

#define PRE_MFMA() do { __builtin_amdgcn_s_barrier();                     \
    asm volatile("s_waitcnt lgkmcnt(0)" ::: "memory");                    \
    __builtin_amdgcn_sched_barrier(0); } while (0)

    // ---- prologue: A(0),B(0) -> buf0 ; A-h0(1) -> As1 ----
    STAGEH(Ap, m0, 0, As0, 0); STAGEH(Ap, m0, 0, As0, 1);
    STAGEH(Bp, n0, 0, Bs0, 0); STAGEH(Bp, n0, 0, Bs0, 1);
    STAGEH(Ap, m0, 1, As1, 0);
    asm volatile("s_waitcnt vmcnt(2)" ::: "memory");
    __builtin_amdgcn_s_barrier();
    __builtin_amdgcn_sched_barrier(0);

    const int niter = nkt >> 1;
    for (int it = 0; it < niter; ++it) {
        const int c1 = 2 * it + 1, c2 = 2 * it + 2, c3 = 2 * it + 3;
        const bool pf = (c2 < nkt);

        // P1
        LDA_M(As0, 0); LDB_M(b0, Bs0, 0);
        STAGEH(Ap, m0, c1, As1, 1);
        STAGEH(Bp, n0, c1, Bs1, 0);
        PRE_MFMA(); MMA_M(b0, 0, 0); __builtin_amdgcn_s_barrier();
        // P2
        LDB_M(b1, Bs0, 1);
        STAGEH(Bp, n0, c1, Bs1, 1);
        PRE_MFMA(); MMA_M(b1, 0, 1); __builtin_amdgcn_s_barrier();
        // P3
        LDA_M(As0, 1);
        if (pf) STAGEH(Bp, n0, c2, Bs0, 0);
        PRE_MFMA(); MMA_M(b1, 1, 1); __builtin_amdgcn_s_barrier();
        // P4
        if (pf) {
            STAGEH(Bp, n0, c2, Bs0, 1);
            asm volatile("s_waitcnt vmcnt(4)" ::: "memory");
        } else {
            asm volatile("s_waitcnt vmcnt(0)" ::: "memory");
        }
        __builtin_amdgcn_s_barrier();
        __builtin_amdgcn_sched_barrier(0);
        MMA_M(b0, 1, 0); __builtin_amdgcn_s_barrier();
        // P5
        LDA_M(As1, 0); LDB_M(b0, Bs1, 0);
        if (pf) STAGEH(Ap, m0, c2, As0, 0);
        PRE_MFMA(); MMA_M(b0, 0, 0); __builtin_amdgcn_s_barrier();
        // P6
        LDB_M(b1, Bs1, 1);
        if (pf) STAGEH(Ap, m0, c2, As0, 1);
        PRE_MFMA(); MMA_M(b1, 0, 1); __builtin_amdgcn_s_barrier();
        // P7
        LDA_M(As1, 1);
        PRE_MFMA(); MMA_M(b1, 1, 1); __builtin_amdgcn_s_barrier();
        // P8
        if (pf) {
            STAGEH(Ap, m0, c3, As1, 0);
            asm volatile("s_waitcnt vmcnt(2)" ::: "memory");
        }
        __builtin_amdgcn_s_barrier();
        __builtin_amdgcn_sched_barrier(0);
        MMA_M(b0, 1, 0); __builtin_amdgcn_s_barrier();
    }

    // ---- epilogue ----
#pragma unroll
    for (int fm = 0; fm < 8; ++fm) {
#pragma unroll
        for (int fn = 0; fn < 4; ++fn) {
            const long gcol = n0 + wn * 64 + fn * 16 + l16;
            float bv = 0.f;
            if (MODE != 0) bv = bias[gcol];
#pragma unroll
            for (int e = 0; e < 4; ++e) {
                const long grow = m0 + wm * 128 + fm * 16 + lg * 4 + e;
                float v = acc[fm][fn][e];
                if (MODE == 0) {
                    ((bf16_t*)outp)[grow * N + gcol] = (bf16_t)v;
                } else if (MODE == 1) {
                    v += bv + ((const float*)addp)[grow * N + gcol];
                    ((float*)outp)[grow * N + gcol] = v;
                } else if (MODE == 2) {
                    v += bv; v = v > 0.f ? v : 0.f;
                    ((bf16_t*)outp)[grow * N + gcol] = (bf16_t)v;
                } else {
                    v += bv + (float)((const bf16_t*)addp)[grow * N + gcol];
                    ((bf16_t*)outp)[grow * N + gcol] = (bf16_t)v;
                }
            }
        }
    }
#undef LDA_M
#undef LDB_M
#undef MMA_M
#undef PRE_MFMA
}

// ---------------- fused causal attention ----------------
// qkv: [B*T, 3072] bf16 (q | k | v each 1024 cols, col = h*64+d)
// out: [B*T, 1024] bf16; 1 block per (b,h); 4 waves; wave w owns Q rows [64w,64w+64)
__global__ __launch_bounds__(256)
void attn_kernel(const bf16_t* __restrict__ qkv, bf16_t* __restrict__ outp)
{
    __shared__ __attribute__((aligned(16))) bf16_t Kt[64 * 72];
    __shared__ __attribute__((aligned(16))) bf16_t Vt[64 * 72];
    __shared__ __attribute__((aligned(16))) bf16_t Ps[4][16 * 72];

    const int tid = threadIdx.x, w = tid >> 6, lane = tid & 63;
    const int l16 = lane & 15, lg = lane >> 4;
    const int b = blockIdx.x >> 4, hh = blockIdx.x & 15;
    const bf16_t* pq = qkv + (long)(b * 256) * 3072 + hh * 64;

    bf16x8 qf[4][2];
#pragma unroll
    for (int fm = 0; fm < 4; ++fm)
#pragma unroll
        for (int kk = 0; kk < 2; ++kk)
            qf[fm][kk] = *(const bf16x8*)(pq + (long)(w * 64 + fm * 16 + l16) * 3072
                                          + kk * 32 + lg * 8);

    f32x4 o[4][4] = {};
    float mrun[4][4], lrun[4][4];
#pragma unroll
    for (int i = 0; i < 4; ++i)
#pragma unroll
        for (int j = 0; j < 4; ++j) { mrun[i][j] = -__builtin_inff(); lrun[i][j] = 0.f; }

    for (int st = 0; st < 4; ++st) {
        __syncthreads();
#pragma unroll
        for (int i = 0; i < 2; ++i) {
            int idx = i * 256 + tid;
            int sr = idx >> 3, sc = (idx & 7) * 8;
            const bf16_t* src = pq + (long)(st * 64 + sr) * 3072;
            bf16x8 kv = *(const bf16x8*)(src + 1024 + sc);
            *(bf16x8*)&Kt[sr * 72 + sc] = kv;
            bf16x8 vv = *(const bf16x8*)(src + 2048 + sc);
#pragma unroll
            for (int e = 0; e < 8; ++e) Vt[(sc + e) * 72 + sr] = vv[e];
        }
        __syncthreads();
        if (st > w) continue;

        f32x4 s[4][4] = {};
#pragma unroll
        for (int ks = 0; ks < 2; ++ks) {
            bf16x8 kb[4];
#pragma unroll
            for (int fs = 0; fs < 4; ++fs)
                kb[fs] = *(const bf16x8*)&Kt[(fs * 16 + l16) * 72 + ks * 32 + lg * 8];
#pragma unroll
            for (int fm = 0; fm < 4; ++fm)
#pragma unroll
                for (int fs = 0; fs < 4; ++fs)
                    s[fm][fs] = __builtin_amdgcn_mfma_f32_16x16x32_bf16(
                        qf[fm][ks], kb[fs], s[fm][fs], 0, 0, 0);
        }

#pragma unroll
        for (int fm = 0; fm < 4; ++fm) {
#pragma unroll
            for (int fs = 0; fs < 4; ++fs)
#pragma unroll
                for (int e = 0; e < 4; ++e) {
                    float v = s[fm][fs][e] * 0.03125f;
                    if (st == w && (fs * 16 + l16) > (fm * 16 + lg * 4 + e))
                        v = -__builtin_inff();
                    s[fm][fs][e] = v;
                }
#pragma unroll
            for (int e = 0; e < 4; ++e) {
                float pm = fmaxf(fmaxf(s[fm][0][e], s[fm][1][e]),
                                 fmaxf(s[fm][2][e], s[fm][3][e]));
#pragma unroll
                for (int off = 1; off < 16; off <<= 1) pm = fmaxf(pm, __shfl_xor(pm, off));
                float mnew  = fmaxf(mrun[fm][e], pm);
                float alpha = __expf(mrun[fm][e] - mnew);
                float rs = 0.f;
#pragma unroll
                for (int fs = 0; fs < 4; ++fs) {
                    float p = __expf(s[fm][fs][e] - mnew);
                    s[fm][fs][e] = p;
                    rs += p;
                }
#pragma unroll
                for (int off = 1; off < 16; off <<= 1) rs += __shfl_xor(rs, off);
                lrun[fm][e] = lrun[fm][e] * alpha + rs;
                mrun[fm][e] = mnew;
#pragma unroll
                for (int fd = 0; fd < 4; ++fd) o[fm][fd][e] *= alpha;
            }
#pragma unroll
            for (int fs = 0; fs < 4; ++fs)
#pragma unroll
                for (int e = 0; e < 4; ++e)
                    Ps[w][(lg * 4 + e) * 72 + fs * 16 + l16] = (bf16_t)s[fm][fs][e];
            bf16x8 ap0 = *(const bf16x8*)&Ps[w][l16 * 72 + lg * 8];
            bf16x8 ap1 = *(const bf16x8*)&Ps[w][l16 * 72 + 32 + lg * 8];
#pragma unroll
            for (int fd = 0; fd < 4; ++fd) {
                bf16x8 vb0 = *(const bf16x8*)&Vt[(fd * 16 + l16) * 72 + lg * 8];
                bf16x8 vb1 = *(const bf16x8*)&Vt[(fd * 16 + l16) * 72 + 32 + lg * 8];
                o[fm][fd] = __builtin_amdgcn_mfma_f32_16x16x32_bf16(ap0, vb0, o[fm][fd], 0, 0, 0);
                o[fm][fd] = __builtin_amdgcn_mfma_f32_16x16x32_bf16(ap1, vb1, o[fm][fd], 0, 0, 0);
            }
        }
    }

#pragma unroll
    for (int fm = 0; fm < 4; ++fm)
#pragma unroll
        for (int e = 0; e < 4; ++e) {
            float inv = 1.f / lrun[fm][e];
            long row = (long)b * 256 + w * 64 + fm * 16 + lg * 4 + e;
#pragma unroll
            for (int fd = 0; fd < 4; ++fd)
                outp[row * 1024 + hh * 64 + fd * 16 + l16] =
                    (bf16_t)(o[fm][fd][e] * inv);
        }
}

// ---------------- launch ----------------
extern "C" void kernel_launch(void* const* d_in, const int* in_sizes, int n_in,
                              void* d_out, int out_size, void* d_ws, size_t ws_size,
                              hipStream_t stream)
{
    (void)in_sizes; (void)n_in; (void)out_size; (void)ws_size;
    const float* x      = (const float*)d_in[0];
    const float* wq     = (const float*)d_in[1];
    const float* wk     = (const float*)d_in[2];
    const float* wv     = (const float*)d_in[3];
    const float* w_proj = (const float*)d_in[4];
    const float* b_proj = (const float*)d_in[5];
    const float* w1     = (const float*)d_in[6];
    const float* b1     = (const float*)d_in[7];
    const float* w2     = (const float*)d_in[8];
    const float* b2     = (const float*)d_in[9];
    const float* g1  = (const float*)d_in[10]; const float* be1 = (const float*)d_in[11];
    const float* g2  = (const float*)d_in[12]; const float* be2 = (const float*)d_in[13];
    const float* g3  = (const float*)d_in[14]; const float* be3 = (const float*)d_in[15];

    char* ws = (char*)d_ws;
    // compact layout, total ~184 MiB:
    bf16_t* wqkv  = (bf16_t*)(ws + 0);           //  6,291,456
    bf16_t* wproj = (bf16_t*)(ws + 6291456);     //  2,097,152
    bf16_t* w1t   = (bf16_t*)(ws + 8388608);     //  8,388,608
    bf16_t* w2t   = (bf16_t*)(ws + 16777216);    //  8,388,608
    bf16_t* h     = (bf16_t*)(ws + 25165824);    // 33,554,432 (LN1 out; later attn out; later start of u)
    bf16_t* qkv   = (bf16_t*)(ws + 58720256);    // 100,663,296
    bf16_t* attn  = h;
    bf16_t* u     = h;                           // 134,217,728 over dead h+qkv
    bf16_t* y     = (bf16_t*)(ws + 159383552);   // 33,554,432 (LN2 out; FFN2 writes in-place)
    float*  x2    = (float*)d_out;
    bf16_t* tbuf  = y;

    const int M = 16384;

    pack_qkv_w<<<12288, 256, 0, stream>>>(wq, wk, wv, wqkv);
    transpose_w<<<4096, 256, 0, stream>>>(w_proj, wproj, 10, 10);
    transpose_w<<<16384, 256, 0, stream>>>(w1, w1t, 10, 12);
    transpose_w<<<16384, 256, 0, stream>>>(w2, w2t, 12, 10);

    // h = LN1(x)
    ln_fwd<<<M, 256, 0, stream>>>(x, g1, be1, h);
    // qkv = h @ Wqkv^T
    gemm_bt<0><<<dim3(64, 12), 512, 0, stream>>>(h, wqkv, qkv, nullptr, nullptr, M, 3072, 1024);
    // attention
    attn_kernel<<<1024, 256, 0, stream>>>(qkv, attn);
    // x2 = x + attn @ Wproj^T + b_proj   -> d_out (f32)
    gemm_bt<1><<<dim3(64, 4), 512, 0, stream>>>(attn, wproj, x2, b_proj, x, M, 1024, 1024);
    // y = LN2(x2)
    ln_fwd<<<M, 256, 0, stream>>>(x2, g2, be2, y);
    // u = relu(y @ W1^T + b1)
    gemm_bt<2><<<dim3(64, 16), 512, 0, stream>>>(y, w1t, u, b1, nullptr, M, 4096, 1024);
    // tbuf = y + (u @ W2^T + b2)  (bf16, in-place over y)
    gemm_bt<3><<<dim3(64, 4), 512, 0, stream>>>(u, w2t, tbuf, b2, y, M, 1024, 4096);
    // d_out = x2 + LN3(tbuf)
    ln3_kernel<<<M, 256, 0, stream>>>(tbuf, g3, be3, (float*)d_out, x2);
}

// Round 9
// 740.455 us; speedup vs baseline: 1.3202x; 1.0334x over previous
//
#include <hip/hip_runtime.h>

typedef __bf16 bf16_t;
typedef __bf16 bf16x8 __attribute__((ext_vector_type(8)));
typedef float f32x4 __attribute__((ext_vector_type(4)));

#define LN_EPS 1e-3f

__device__ __forceinline__ void gload_lds16(const void* g, void* l) {
    __builtin_amdgcn_global_load_lds(
        (__attribute__((address_space(1))) void*)(g),
        (__attribute__((address_space(3))) void*)(l), 16, 0, 0);
}

// ---------------- weight prep ----------------
__global__ void pack_qkv_w(const float* __restrict__ wq, const float* __restrict__ wk,
                           const float* __restrict__ wv, bf16_t* __restrict__ outp)
{
    int idx = blockIdx.x * 256 + threadIdx.x;
    int c   = idx & 1023;
    int n   = idx >> 10;
    int sel = n >> 10;
    int hd  = n & 1023;
    const float* src = (sel == 0) ? wq : (sel == 1) ? wk : wv;
    outp[idx] = (bf16_t)src[((hd >> 6) * 1024 + c) * 64 + (hd & 63)];
}

__global__ void transpose_w(const float* __restrict__ in, bf16_t* __restrict__ outp,
                            int lgK, int lgN)
{
    long idx = (long)blockIdx.x * 256 + threadIdx.x;
    long k = idx & ((1L << lgK) - 1);
    long n = idx >> lgK;
    outp[idx] = (bf16_t)in[n + (k << lgN)];
}

// vt[(b*16+h)*64 + d][s] = v[b*256+s][h*64+d] ; v = qkv cols 2048..3071
__global__ __launch_bounds__(256)
void v_transpose(const bf16_t* __restrict__ qkv, bf16_t* __restrict__ vt)
{
    int g  = blockIdx.x * 256 + threadIdx.x;   // 8192 blocks x 256
    int bh = g >> 11;                          // 0..1023
    int r  = g & 2047;
    int d  = r & 63;
    int sg = r >> 6;                           // 0..31
    int b  = bh >> 4, h = bh & 15;
    const bf16_t* src = qkv + ((long)b * 256 + sg * 8) * 3072 + 2048 + h * 64 + d;
    union { bf16_t e[8]; uint4 u; } pk;
#pragma unroll
    for (int e = 0; e < 8; ++e) pk.e[e] = src[(long)e * 3072];
    *(uint4*)(vt + ((long)bh * 64 + d) * 256 + sg * 8) = pk.u;
}

// ---------------- layernorm (f32 in -> bf16 LN out) ----------------
__global__ __launch_bounds__(256)
void ln_fwd(const float* __restrict__ in, const float* __restrict__ g,
            const float* __restrict__ be, bf16_t* __restrict__ outp)
{
    const long row = blockIdx.x;
    const int t = threadIdx.x;
    float4 v = ((const float4*)(in + row * 1024))[t];
    float s  = v.x + v.y + v.z + v.w;
    float sq = v.x * v.x + v.y * v.y + v.z * v.z + v.w * v.w;
#pragma unroll
    for (int off = 1; off < 64; off <<= 1) {
        s  += __shfl_xor(s, off);
        sq += __shfl_xor(sq, off);
    }
    __shared__ float red[8];
    if ((t & 63) == 0) { red[(t >> 6) * 2] = s; red[(t >> 6) * 2 + 1] = sq; }
    __syncthreads();
    s  = red[0] + red[2] + red[4] + red[6];
    sq = red[1] + red[3] + red[5] + red[7];
    float mean = s * 0.0009765625f;
    float var  = sq * 0.0009765625f - mean * mean;
    float rstd = rsqrtf(var + LN_EPS);
    float4 gv = ((const float4*)g)[t];
    float4 bv = ((const float4*)be)[t];
    union { bf16_t h[4]; uint2 u; } pk;
    pk.h[0] = (bf16_t)((v.x - mean) * rstd * gv.x + bv.x);
    pk.h[1] = (bf16_t)((v.y - mean) * rstd * gv.y + bv.y);
    pk.h[2] = (bf16_t)((v.z - mean) * rstd * gv.z + bv.z);
    pk.h[3] = (bf16_t)((v.w - mean) * rstd * gv.w + bv.w);
    *(uint2*)(outp + row * 1024 + t * 4) = pk.u;
}

// ---------------- final layernorm (bf16 in + f32 res -> f32 out) ----------------
__global__ __launch_bounds__(256)
void ln3_kernel(const bf16_t* __restrict__ in, const float* __restrict__ g,
                const float* __restrict__ be, float* outp, const float* res)
{
    const long row = blockIdx.x;
    const int t = threadIdx.x;
    union { uint2 u; bf16_t h[4]; } pk;
    pk.u = *(const uint2*)(in + row * 1024 + t * 4);
    float v0 = (float)pk.h[0], v1 = (float)pk.h[1], v2 = (float)pk.h[2], v3 = (float)pk.h[3];
    float s  = v0 + v1 + v2 + v3;
    float sq = v0 * v0 + v1 * v1 + v2 * v2 + v3 * v3;
#pragma unroll
    for (int off = 1; off < 64; off <<= 1) {
        s  += __shfl_xor(s, off);
        sq += __shfl_xor(sq, off);
    }
    __shared__ float red[8];
    if ((t & 63) == 0) { red[(t >> 6) * 2] = s; red[(t >> 6) * 2 + 1] = sq; }
    __syncthreads();
    s  = red[0] + red[2] + red[4] + red[6];
    sq = red[1] + red[3] + red[5] + red[7];
    float mean = s * 0.0009765625f;
    float var  = sq * 0.0009765625f - mean * mean;
    float rstd = rsqrtf(var + LN_EPS);
    float4 gv = ((const float4*)g)[t];
    float4 bv = ((const float4*)be)[t];
    float4 rv = ((const float4*)(res + row * 1024))[t];
    float4 ov;
    ov.x = rv.x + (v0 - mean) * rstd * gv.x + bv.x;
    ov.y = rv.y + (v1 - mean) * rstd * gv.y + bv.y;
    ov.z = rv.z + (v2 - mean) * rstd * gv.z + bv.z;
    ov.w = rv.w + (v3 - mean) * rstd * gv.w + bv.w;
    ((float4*)outp)[row * 256 + t] = ov;
}

// ---------------- GEMM: C[M,N] = A[M,K] * Bt[N,K]^T ----------------
// 256x256 tile, BK=64, 512 threads = 8 waves; 8-phase schedule, 2 LDS K-tile
// buffers (128 KB). Ledger & swizzle as round-8 (verified, 0 conflicts).
// XCD swizzle: same-XCD blocks share the A panel (m0), iterate n fastest.
template<int MODE>
__global__ __launch_bounds__(512, 2)
void gemm_bt(const bf16_t* __restrict__ Ap, const bf16_t* __restrict__ Bp,
             void* outp, const float* __restrict__ bias,
             const void* addp, int M, int N, int K)
{
    __shared__ __attribute__((aligned(16))) bf16_t As0[256 * 64];
    __shared__ __attribute__((aligned(16))) bf16_t As1[256 * 64];
    __shared__ __attribute__((aligned(16))) bf16_t Bs0[256 * 64];
    __shared__ __attribute__((aligned(16))) bf16_t Bs1[256 * 64];

    const int tid  = threadIdx.x;
    const int w    = tid >> 6, lane = tid & 63;
    const int l16  = lane & 15, lg = lane >> 4;
    const int wm   = w >> 2, wn = w & 3;
    const int srow = lane >> 3;          // 0..7
    const int sslot = lane & 7;          // 16B slot within 128B row

    // XCD-aware swizzle; consecutive sid (same XCD) share m0 -> A-panel L2 reuse
    const int gx  = gridDim.x;
    const int gy  = gridDim.y;
    const int nwg = gx * gy;
    const int bid = blockIdx.y * gx + blockIdx.x;
    const int cpx = nwg >> 3;
    const int sid = (bid & 7) * cpx + (bid >> 3);
    const long m0 = (long)(sid / gy) * 256;
    const long n0 = (long)(sid % gy) * 256;
    const int nkt = K >> 6;

    f32x4 acc[8][4] = {};
    bf16x8 a[4][2], b0[2][2], b1[2][2];

    auto STAGEH = [&](const bf16_t* src, long row0, int kt, bf16_t* dst, int h) {
#pragma unroll
        for (int i = 0; i < 2; ++i) {
            int r  = h * 128 + w * 16 + i * 8 + srow;
            int ss = sslot ^ (r & 7);
            gload_lds16(src + (row0 + r) * (long)K + (long)kt * 64 + ss * 8,
                        dst + (h * 128 + w * 16 + i * 8) * 64);
        }
    };

#define LDA_M(buf, mh) do {                                               \
    _Pragma("unroll") for (int j = 0; j < 4; ++j)                         \
    _Pragma("unroll") for (int kk = 0; kk < 2; ++kk) {                    \
        int r  = wm * 128 + (mh) * 64 + j * 16 + l16;                     \
        int ss = (kk * 4 + lg) ^ (r & 7);                                 \
        a[j][kk] = *(const bf16x8*)&buf[r * 64 + ss * 8];                 \
    } } while (0)

#define LDB_M(dst, buf, nh) do {                                          \
    _Pragma("unroll") for (int n = 0; n < 2; ++n)                         \
    _Pragma("unroll") for (int kk = 0; kk < 2; ++kk) {                    \
        int r  = wn * 64 + ((nh) * 2 + n) * 16 + l16;                     \
        int ss = (kk * 4 + lg) ^ (r & 7);                                 \
        dst[n][kk] = *(const bf16x8*)&buf[r * 64 + ss * 8];               \
    } } while (0)

#define MMA_M(bv, mh, nh) do {                                            \
    __builtin_amdgcn_s_setprio(1);                                        \
    _Pragma("unroll") for (int j = 0; j < 4; ++j)                         \
    _Pragma("unroll") for (int n = 0; n < 2; ++n)                         \
    _Pragma("unroll") for (int kk = 0; kk < 2; ++kk)                      \
        acc[(mh) * 4 + j][(nh) * 2 + n] =                                 \
            __builtin_amdgcn_mfma_f32_16x16x32_bf16(                      \
                a[j][kk], bv[n][kk], acc[(mh) * 4 + j][(nh) * 2 + n],     \
                0, 0, 0);                                                 \
    __builtin_amdgcn_s_setprio(0);                                        \
} while (0)

#define PRE_MFMA() do { __builtin_amdgcn_s_barrier();                     \
    asm volatile("s_waitcnt lgkmcnt(0)" ::: "memory");                    \
    __builtin_amdgcn_sched_barrier(0); } while (0)

    // ---- prologue ----
    STAGEH(Ap, m0, 0, As0, 0); STAGEH(Ap, m0, 0, As0, 1);
    STAGEH(Bp, n0, 0, Bs0, 0); STAGEH(Bp, n0, 0, Bs0, 1);
    STAGEH(Ap, m0, 1, As1, 0);
    asm volatile("s_waitcnt vmcnt(2)" ::: "memory");
    __builtin_amdgcn_s_barrier();
    __builtin_amdgcn_sched_barrier(0);

    const int niter = nkt >> 1;
    for (int it = 0; it < niter; ++it) {
        const int c1 = 2 * it + 1, c2 = 2 * it + 2, c3 = 2 * it + 3;
        const bool pf = (c2 < nkt);

        // P1
        LDA_M(As0, 0); LDB_M(b0, Bs0, 0);
        STAGEH(Ap, m0, c1, As1, 1);
        STAGEH(Bp, n0, c1, Bs1, 0);
        PRE_MFMA(); MMA_M(b0, 0, 0); __builtin_amdgcn_s_barrier();
        // P2
        LDB_M(b1, Bs0, 1);
        STAGEH(Bp, n0, c1, Bs1, 1);
        PRE_MFMA(); MMA_M(b1, 0, 1); __builtin_amdgcn_s_barrier();
        // P3
        LDA_M(As0, 1);
        if (pf) STAGEH(Bp, n0, c2, Bs0, 0);
        PRE_MFMA(); MMA_M(b1, 1, 1); __builtin_amdgcn_s_barrier();
        // P4
        if (pf) {
            STAGEH(Bp, n0, c2, Bs0, 1);
            asm volatile("s_waitcnt vmcnt(4)" ::: "memory");
        } else {
            asm volatile("s_waitcnt vmcnt(0)" ::: "memory");
        }
        __builtin_amdgcn_s_barrier();
        __builtin_amdgcn_sched_barrier(0);
        MMA_M(b0, 1, 0); __builtin_amdgcn_s_barrier();
        // P5
        LDA_M(As1, 0); LDB_M(b0, Bs1, 0);
        if (pf) STAGEH(Ap, m0, c2, As0, 0);
        PRE_MFMA(); MMA_M(b0, 0, 0); __builtin_amdgcn_s_barrier();
        // P6
        LDB_M(b1, Bs1, 1);
        if (pf) STAGEH(Ap, m0, c2, As0, 1);
        PRE_MFMA(); MMA_M(b1, 0, 1); __builtin_amdgcn_s_barrier();
        // P7
        LDA_M(As1, 1);
        PRE_MFMA(); MMA_M(b1, 1, 1); __builtin_amdgcn_s_barrier();
        // P8
        if (pf) {
            STAGEH(Ap, m0, c3, As1, 0);
            asm volatile("s_waitcnt vmcnt(2)" ::: "memory");
        }
        __builtin_amdgcn_s_barrier();
        __builtin_amdgcn_sched_barrier(0);
        MMA_M(b0, 1, 0); __builtin_amdgcn_s_barrier();
    }

    // ---- epilogue ----
#pragma unroll
    for (int fm = 0; fm < 8; ++fm) {
#pragma unroll
        for (int fn = 0; fn < 4; ++fn) {
            const long gcol = n0 + wn * 64 + fn * 16 + l16;
            float bv = 0.f;
            if (MODE != 0) bv = bias[gcol];
#pragma unroll
            for (int e = 0; e < 4; ++e) {
                const long grow = m0 + wm * 128 + fm * 16 + lg * 4 + e;
                float v = acc[fm][fn][e];
                if (MODE == 0) {
                    ((bf16_t*)outp)[grow * N + gcol] = (bf16_t)v;
                } else if (MODE == 1) {
                    v += bv + ((const float*)addp)[grow * N + gcol];
                    ((float*)outp)[grow * N + gcol] = v;
                } else if (MODE == 2) {
                    v += bv; v = v > 0.f ? v : 0.f;
                    ((bf16_t*)outp)[grow * N + gcol] = (bf16_t)v;
                } else {
                    v += bv + (float)((const bf16_t*)addp)[grow * N + gcol];
                    ((bf16_t*)outp)[grow * N + gcol] = (bf16_t)v;
                }
            }
        }
    }
#undef LDA_M
#undef LDB_M
#undef MMA_M
#undef PRE_MFMA
}

// ---------------- fused causal attention ----------------
// qkv: [B*T, 3072] bf16; vt: [B*H, 64, 256] bf16 (V^T, s-contig)
// out: [B*T, 1024] bf16; 1 block per (b,h); 4 waves; wave w owns Q rows [64w,64w+64)
// K and V^T staged via global_load_lds with XOR slot swizzle (linear LDS dest,
// inverse swizzle on global source; read applies same involution).
__global__ __launch_bounds__(256)
void attn_kernel(const bf16_t* __restrict__ qkv, const bf16_t* __restrict__ vt,
                 bf16_t* __restrict__ outp)
{
    __shared__ __attribute__((aligned(16))) bf16_t Kt[64 * 64];
    __shared__ __attribute__((aligned(16))) bf16_t Vt[64 * 64];
    __shared__ __attribute__((aligned(16))) bf16_t Ps[4][16 * 72];

    const int tid = threadIdx.x, w = tid >> 6, lane = tid & 63;
    const int l16 = lane & 15, lg = lane >> 4;
    const int b = blockIdx.x >> 4, hh = blockIdx.x & 15;
    const bf16_t* pq = qkv + (long)(b * 256) * 3072 + hh * 64;
    const bf16_t* pv = vt + (long)blockIdx.x * 64 * 256;
    const int sr8 = lane >> 3;     // 0..7
    const int sl  = lane & 7;

    bf16x8 qf[4][2];
#pragma unroll
    for (int fm = 0; fm < 4; ++fm)
#pragma unroll
        for (int kk = 0; kk < 2; ++kk)
            qf[fm][kk] = *(const bf16x8*)(pq + (long)(w * 64 + fm * 16 + l16) * 3072
                                          + kk * 32 + lg * 8);

    f32x4 o[4][4] = {};
    float mrun[4][4], lrun[4][4];
#pragma unroll
    for (int i = 0; i < 4; ++i)
#pragma unroll
        for (int j = 0; j < 4; ++j) { mrun[i][j] = -__builtin_inff(); lrun[i][j] = 0.f; }

    for (int st = 0; st < 4; ++st) {
        __syncthreads();
        // stage K [64s x 64d] and V^T [64d x 64s] via global_load_lds; wave w
        // covers LDS rows [w*16, w*16+16)
#pragma unroll
        for (int i = 0; i < 2; ++i) {
            int r  = w * 16 + i * 8 + sr8;
            int ss = sl ^ (r & 7);
            gload_lds16(pq + (long)(st * 64 + r) * 3072 + 1024 + ss * 8,
                        &Kt[(w * 16 + i * 8) * 64]);
            gload_lds16(pv + (long)r * 256 + st * 64 + ss * 8,
                        &Vt[(w * 16 + i * 8) * 64]);
        }
        asm volatile("s_waitcnt vmcnt(0)" ::: "memory");
        __syncthreads();
        if (st > w) continue;

        // S = Q K^T   (swizzled K reads)
        f32x4 s[4][4] = {};
#pragma unroll
        for (int ks = 0; ks < 2; ++ks) {
            bf16x8 kb[4];
#pragma unroll
            for (int fs = 0; fs < 4; ++fs)
                kb[fs] = *(const bf16x8*)&Kt[(fs * 16 + l16) * 64
                                             + ((ks * 4 + lg) ^ (l16 & 7)) * 8];
#pragma unroll
            for (int fm = 0; fm < 4; ++fm)
#pragma unroll
                for (int fs = 0; fs < 4; ++fs)
                    s[fm][fs] = __builtin_amdgcn_mfma_f32_16x16x32_bf16(
                        qf[fm][ks], kb[fs], s[fm][fs], 0, 0, 0);
        }

#pragma unroll
        for (int fm = 0; fm < 4; ++fm) {
#pragma unroll
            for (int fs = 0; fs < 4; ++fs)
#pragma unroll
                for (int e = 0; e < 4; ++e) {
                    float v = s[fm][fs][e] * 0.03125f;
                    if (st == w && (fs * 16 + l16) > (fm * 16 + lg * 4 + e))
                        v = -__builtin_inff();
                    s[fm][fs][e] = v;
                }
#pragma unroll
            for (int e = 0; e < 4; ++e) {
                float pm = fmaxf(fmaxf(s[fm][0][e], s[fm][1][e]),
                                 fmaxf(s[fm][2][e], s[fm][3][e]));
#pragma unroll
                for (int off = 1; off < 16; off <<= 1) pm = fmaxf(pm, __shfl_xor(pm, off));
                float mnew  = fmaxf(mrun[fm][e], pm);
                float alpha = __expf(mrun[fm][e] - mnew);
                float rs = 0.f;
#pragma unroll
                for (int fs = 0; fs < 4; ++fs) {
                    float p = __expf(s[fm][fs][e] - mnew);
                    s[fm][fs][e] = p;
                    rs += p;
                }
#pragma unroll
                for (int off = 1; off < 16; off <<= 1) rs += __shfl_xor(rs, off);
                lrun[fm][e] = lrun[fm][e] * alpha + rs;
                mrun[fm][e] = mnew;
#pragma unroll
                for (int fd = 0; fd < 4; ++fd) o[fm][fd][e] *= alpha;
            }
#pragma unroll
            for (int fs = 0; fs < 4; ++fs)
#pragma unroll
                for (int e = 0; e < 4; ++e)
                    Ps[w][(lg * 4 + e) * 72 + fs * 16 + l16] = (bf16_t)s[fm][fs][e];
            bf16x8 ap0 = *(const bf16x8*)&Ps[w][l16 * 72 + lg * 8];
            bf16x8 ap1 = *(const bf16x8*)&Ps[w][l16 * 72 + 32 + lg * 8];
#pragma unroll
            for (int fd = 0; fd < 4; ++fd) {
                bf16x8 vb0 = *(const bf16x8*)&Vt[(fd * 16 + l16) * 64
                                                 + ((lg) ^ (l16 & 7)) * 8];
                bf16x8 vb1 = *(const bf16x8*)&Vt[(fd * 16 + l16) * 64
                                                 + ((4 + lg) ^ (l16 & 7)) * 8];
                o[fm][fd] = __builtin_amdgcn_mfma_f32_16x16x32_bf16(ap0, vb0, o[fm][fd], 0, 0, 0);
                o[fm][fd] = __builtin_amdgcn_mfma_f32_16x16x32_bf16(ap1, vb1, o[fm][fd], 0, 0, 0);
            }
        }
    }

#pragma unroll
    for (int fm = 0; fm < 4; ++fm)
#pragma unroll
        for (int e = 0; e < 4; ++e) {
            float inv = 1.f / lrun[fm][e];
            long row = (long)b * 256 + w * 64 + fm * 16 + lg * 4 + e;
#pragma unroll
            for (int fd = 0; fd < 4; ++fd)
                outp[row * 1024 + hh * 64 + fd * 16 + l16] =
                    (bf16_t)(o[fm][fd][e] * inv);
        }
}

// ---------------- launch ----------------
extern "C" void kernel_launch(void* const* d_in, const int* in_sizes, int n_in,
                              void* d_out, int out_size, void* d_ws, size_t ws_size,
                              hipStream_t stream)
{
    (void)in_sizes; (void)n_in; (void)out_size; (void)ws_size;
    const float* x      = (const float*)d_in[0];
    const float* wq     = (const float*)d_in[1];
    const float* wk     = (const float*)d_in[2];
    const float* wv     = (const float*)d_in[3];
    const float* w_proj = (const float*)d_in[4];
    const float* b_proj = (const float*)d_in[5];
    const float* w1     = (const float*)d_in[6];
    const float* b1     = (const float*)d_in[7];
    const float* w2     = (const float*)d_in[8];
    const float* b2     = (const float*)d_in[9];
    const float* g1  = (const float*)d_in[10]; const float* be1 = (const float*)d_in[11];
    const float* g2  = (const float*)d_in[12]; const float* be2 = (const float*)d_in[13];
    const float* g3  = (const float*)d_in[14]; const float* be3 = (const float*)d_in[15];

    char* ws = (char*)d_ws;
    // compact layout, total ~184 MiB:
    bf16_t* wqkv  = (bf16_t*)(ws + 0);           //  6,291,456
    bf16_t* wproj = (bf16_t*)(ws + 6291456);     //  2,097,152
    bf16_t* w1t   = (bf16_t*)(ws + 8388608);     //  8,388,608
    bf16_t* w2t   = (bf16_t*)(ws + 16777216);    //  8,388,608
    bf16_t* h     = (bf16_t*)(ws + 25165824);    // 33,554,432 (LN1 out; attn out; start of u)
    bf16_t* qkv   = (bf16_t*)(ws + 58720256);    // 100,663,296
    bf16_t* attn  = h;
    bf16_t* u     = h;                           // 134,217,728 over dead h+qkv
    bf16_t* y     = (bf16_t*)(ws + 159383552);   // 33,554,432 (vt before LN2; y after)
    bf16_t* vt    = y;                           // V^T lives here until proj GEMM done
    float*  x2    = (float*)d_out;
    bf16_t* tbuf  = y;

    const int M = 16384;

    pack_qkv_w<<<12288, 256, 0, stream>>>(wq, wk, wv, wqkv);
    transpose_w<<<4096, 256, 0, stream>>>(w_proj, wproj, 10, 10);
    transpose_w<<<16384, 256, 0, stream>>>(w1, w1t, 10, 12);
    transpose_w<<<16384, 256, 0, stream>>>(w2, w2t, 12, 10);

    // h = LN1(x)
    ln_fwd<<<M, 256, 0, stream>>>(x, g1, be1, h);
    // qkv = h @ Wqkv^T
    gemm_bt<0><<<dim3(64, 12), 512, 0, stream>>>(h, wqkv, qkv, nullptr, nullptr, M, 3072, 1024);
    // vt = V^T  (per (b,h): [64d][256s])
    v_transpose<<<8192, 256, 0, stream>>>(qkv, vt);
    // attention
    attn_kernel<<<1024, 256, 0, stream>>>(qkv, vt, attn);
    // x2 = x + attn @ Wproj^T + b_proj   -> d_out (f32)
    gemm_bt<1><<<dim3(64, 4), 512, 0, stream>>>(attn, wproj, x2, b_proj, x, M, 1024, 1024);
    // y = LN2(x2)   (overwrites vt, now dead)
    ln_fwd<<<M, 256, 0, stream>>>(x2, g2, be2, y);
    // u = relu(y @ W1^T + b1)
    gemm_bt<2><<<dim3(64, 16), 512, 0, stream>>>(y, w1t, u, b1, nullptr, M, 4096, 1024);
    // tbuf = y + (u @ W2^T + b2)  (bf16, in-place over y)
    gemm_bt<3><<<dim3(64, 4), 512, 0, stream>>>(u, w2t, tbuf, b2, y, M, 1024, 4096);
    // d_out = x2 + LN3(tbuf)
    ln3_kernel<<<M, 256, 0, stream>>>(tbuf, g3, be3, (float*)d_out, x2);
}

// Round 10
// 681.337 us; speedup vs baseline: 1.4347x; 1.0868x over previous
//
#include <hip/hip_runtime.h>

typedef __bf16 bf16_t;
typedef __bf16 bf16x8 __attribute__((ext_vector_type(8)));
typedef float f32x4 __attribute__((ext_vector_type(4)));

#define LN_EPS 1e-3f

__device__ __forceinline__ void gload_lds16(const void* g, void* l) {
    __builtin_amdgcn_global_load_lds(
        (__attribute__((address_space(1))) void*)(g),
        (__attribute__((address_space(3))) void*)(l), 16, 0, 0);
}

// ---------------- weight prep (LDS-tiled, coalesced both sides) ----------------
// out[n*ldo + k] = (bf16)in[k*ldi + n], 64x64 tile per block.
// Read: 4 threads x 4 float4 per row (coalesced). LDS f32 [64][65] (odd stride,
// conflict-free column reads). Write: 16 bf16 packed -> 2x uint4 per thread.
__global__ __launch_bounds__(256)
void transpose_f32_bf16(const float* __restrict__ in, bf16_t* __restrict__ outp,
                        int ldi, int ldo)
{
    __shared__ float tile[64][65];
    const int k0 = blockIdx.x * 64, n0 = blockIdx.y * 64;
    const int tid = threadIdx.x;
    const int r = tid >> 2;      // 0..63
    const int q = tid & 3;       // 0..3 (16 cols each)
    const float* src = in + (long)(k0 + r) * ldi + n0 + q * 16;
#pragma unroll
    for (int j = 0; j < 4; ++j) {
        float4 v = *(const float4*)(src + j * 4);
        tile[r][q * 16 + j * 4 + 0] = v.x;
        tile[r][q * 16 + j * 4 + 1] = v.y;
        tile[r][q * 16 + j * 4 + 2] = v.z;
        tile[r][q * 16 + j * 4 + 3] = v.w;
    }
    __syncthreads();
    union { bf16_t e[16]; uint4 u[2]; } pk;
#pragma unroll
    for (int j = 0; j < 16; ++j) pk.e[j] = (bf16_t)tile[q * 16 + j][r];
    bf16_t* dst = outp + (long)(n0 + r) * ldo + k0 + q * 16;
    *(uint4*)(dst)     = pk.u[0];
    *(uint4*)(dst + 8) = pk.u[1];
}

// wqkv[(sel*1024 + h*64 + d)*1024 + c] = w_sel[h][c][d]; per (sel,h) it's a
// [1024c x 64d] -> [64d x 1024c] transpose. grid (16 kTiles, 48 mats).
__global__ __launch_bounds__(256)
void pack_qkv_t(const float* __restrict__ wq, const float* __restrict__ wk,
                const float* __restrict__ wv, bf16_t* __restrict__ outp)
{
    __shared__ float tile[64][65];
    const int m   = blockIdx.y;           // 0..47
    const int sel = m >> 4, h = m & 15;
    const float* in = ((sel == 0) ? wq : (sel == 1) ? wk : wv) + (long)h * 65536;
    bf16_t* out = outp + ((long)sel * 1024 + h * 64) * 1024;
    const int k0 = blockIdx.x * 64;       // c-tile
    const int tid = threadIdx.x;
    const int r = tid >> 2;
    const int q = tid & 3;
    const float* src = in + (long)(k0 + r) * 64 + q * 16;
#pragma unroll
    for (int j = 0; j < 4; ++j) {
        float4 v = *(const float4*)(src + j * 4);
        tile[r][q * 16 + j * 4 + 0] = v.x;
        tile[r][q * 16 + j * 4 + 1] = v.y;
        tile[r][q * 16 + j * 4 + 2] = v.z;
        tile[r][q * 16 + j * 4 + 3] = v.w;
    }
    __syncthreads();
    union { bf16_t e[16]; uint4 u[2]; } pk;
#pragma unroll
    for (int j = 0; j < 16; ++j) pk.e[j] = (bf16_t)tile[q * 16 + j][r];
    bf16_t* dst = out + (long)r * 1024 + k0 + q * 16;
    *(uint4*)(dst)     = pk.u[0];
    *(uint4*)(dst + 8) = pk.u[1];
}

// vt[(b*16+h)*64 + d][s] = v[b*256+s][h*64+d] ; v = qkv cols 2048..3071
__global__ __launch_bounds__(256)
void v_transpose(const bf16_t* __restrict__ qkv, bf16_t* __restrict__ vt)
{
    int g  = blockIdx.x * 256 + threadIdx.x;
    int bh = g >> 11;
    int r  = g & 2047;
    int d  = r & 63;
    int sg = r >> 6;
    int b  = bh >> 4, h = bh & 15;
    const bf16_t* src = qkv + ((long)b * 256 + sg * 8) * 3072 + 2048 + h * 64 + d;
    union { bf16_t e[8]; uint4 u; } pk;
#pragma unroll
    for (int e = 0; e < 8; ++e) pk.e[e] = src[(long)e * 3072];
    *(uint4*)(vt + ((long)bh * 64 + d) * 256 + sg * 8) = pk.u;
}

// ---------------- layernorm (f32 in -> bf16 LN out) ----------------
__global__ __launch_bounds__(256)
void ln_fwd(const float* __restrict__ in, const float* __restrict__ g,
            const float* __restrict__ be, bf16_t* __restrict__ outp)
{
    const long row = blockIdx.x;
    const int t = threadIdx.x;
    float4 v = ((const float4*)(in + row * 1024))[t];
    float s  = v.x + v.y + v.z + v.w;
    float sq = v.x * v.x + v.y * v.y + v.z * v.z + v.w * v.w;
#pragma unroll
    for (int off = 1; off < 64; off <<= 1) {
        s  += __shfl_xor(s, off);
        sq += __shfl_xor(sq, off);
    }
    __shared__ float red[8];
    if ((t & 63) == 0) { red[(t >> 6) * 2] = s; red[(t >> 6) * 2 + 1] = sq; }
    __syncthreads();
    s  = red[0] + red[2] + red[4] + red[6];
    sq = red[1] + red[3] + red[5] + red[7];
    float mean = s * 0.0009765625f;
    float var  = sq * 0.0009765625f - mean * mean;
    float rstd = rsqrtf(var + LN_EPS);
    float4 gv = ((const float4*)g)[t];
    float4 bv = ((const float4*)be)[t];
    union { bf16_t h[4]; uint2 u; } pk;
    pk.h[0] = (bf16_t)((v.x - mean) * rstd * gv.x + bv.x);
    pk.h[1] = (bf16_t)((v.y - mean) * rstd * gv.y + bv.y);
    pk.h[2] = (bf16_t)((v.z - mean) * rstd * gv.z + bv.z);
    pk.h[3] = (bf16_t)((v.w - mean) * rstd * gv.w + bv.w);
    *(uint2*)(outp + row * 1024 + t * 4) = pk.u;
}

// ---------------- final layernorm (bf16 in + f32 res -> f32 out) ----------------
__global__ __launch_bounds__(256)
void ln3_kernel(const bf16_t* __restrict__ in, const float* __restrict__ g,
                const float* __restrict__ be, float* outp, const float* res)
{
    const long row = blockIdx.x;
    const int t = threadIdx.x;
    union { uint2 u; bf16_t h[4]; } pk;
    pk.u = *(const uint2*)(in + row * 1024 + t * 4);
    float v0 = (float)pk.h[0], v1 = (float)pk.h[1], v2 = (float)pk.h[2], v3 = (float)pk.h[3];
    float s  = v0 + v1 + v2 + v3;
    float sq = v0 * v0 + v1 * v1 + v2 * v2 + v3 * v3;
#pragma unroll
    for (int off = 1; off < 64; off <<= 1) {
        s  += __shfl_xor(s, off);
        sq += __shfl_xor(sq, off);
    }
    __shared__ float red[8];
    if ((t & 63) == 0) { red[(t >> 6) * 2] = s; red[(t >> 6) * 2 + 1] = sq; }
    __syncthreads();
    s  = red[0] + red[2] + red[4] + red[6];
    sq = red[1] + red[3] + red[5] + red[7];
    float mean = s * 0.0009765625f;
    float var  = sq * 0.0009765625f - mean * mean;
    float rstd = rsqrtf(var + LN_EPS);
    float4 gv = ((const float4*)g)[t];
    float4 bv = ((const float4*)be)[t];
    float4 rv = ((const float4*)(res + row * 1024))[t];
    float4 ov;
    ov.x = rv.x + (v0 - mean) * rstd * gv.x + bv.x;
    ov.y = rv.y + (v1 - mean) * rstd * gv.y + bv.y;
    ov.z = rv.z + (v2 - mean) * rstd * gv.z + bv.z;
    ov.w = rv.w + (v3 - mean) * rstd * gv.w + bv.w;
    ((float4*)outp)[row * 256 + t] = ov;
}

// ---------------- GEMM: C[M,N] = A[M,K] * Bt[N,K]^T ----------------
// 256x256 tile, BK=64, 512 threads = 8 waves; 8-phase schedule, 2 LDS K-tile
// buffers (128 KB). Ledger & swizzle as round-8 (verified, 0 conflicts).
// XCD swizzle: same-XCD blocks share the A panel (m0), iterate n fastest.
template<int MODE>
__global__ __launch_bounds__(512, 2)
void gemm_bt(const bf16_t* __restrict__ Ap, const bf16_t* __restrict__ Bp,
             void* outp, const float* __restrict__ bias,
             const void* addp, int M, int N, int K)
{
    __shared__ __attribute__((aligned(16))) bf16_t As0[256 * 64];
    __shared__ __attribute__((aligned(16))) bf16_t As1[256 * 64];
    __shared__ __attribute__((aligned(16))) bf16_t Bs0[256 * 64];
    __shared__ __attribute__((aligned(16))) bf16_t Bs1[256 * 64];

    const int tid  = threadIdx.x;
    const int w    = tid >> 6, lane = tid & 63;
    const int l16  = lane & 15, lg = lane >> 4;
    const int wm   = w >> 2, wn = w & 3;
    const int srow = lane >> 3;          // 0..7
    const int sslot = lane & 7;          // 16B slot within 128B row

    const int gx  = gridDim.x;
    const int gy  = gridDim.y;
    const int nwg = gx * gy;
    const int bid = blockIdx.y * gx + blockIdx.x;
    const int cpx = nwg >> 3;
    const int sid = (bid & 7) * cpx + (bid >> 3);
    const long m0 = (long)(sid / gy) * 256;
    const long n0 = (long)(sid % gy) * 256;
    const int nkt = K >> 6;

    f32x4 acc[8][4] = {};
    bf16x8 a[4][2], b0[2][2], b1[2][2];

    auto STAGEH = [&](const bf16_t* src, long row0, int kt, bf16_t* dst, int h) {
#pragma unroll
        for (int i = 0; i < 2; ++i) {
            int r  = h * 128 + w * 16 + i * 8 + srow;
            int ss = sslot ^ (r & 7);
            gload_lds16(src + (row0 + r) * (long)K + (long)kt * 64 + ss * 8,
                        dst + (h * 128 + w * 16 + i * 8) * 64);
        }
    };

#define LDA_M(buf, mh) do {                                               \
    _Pragma("unroll") for (int j = 0; j < 4; ++j)                         \
    _Pragma("unroll") for (int kk = 0; kk < 2; ++kk) {                    \
        int r  = wm * 128 + (mh) * 64 + j * 16 + l16;                     \
        int ss = (kk * 4 + lg) ^ (r & 7);                                 \
        a[j][kk] = *(const bf16x8*)&buf[r * 64 + ss * 8];                 \
    } } while (0)

#define LDB_M(dst, buf, nh) do {                                          \
    _Pragma("unroll") for (int n = 0; n < 2; ++n)                         \
    _Pragma("unroll") for (int kk = 0; kk < 2; ++kk) {                    \
        int r  = wn * 64 + ((nh) * 2 + n) * 16 + l16;                     \
        int ss = (kk * 4 + lg) ^ (r & 7);                                 \
        dst[n][kk] = *(const bf16x8*)&buf[r * 64 + ss * 8];               \
    } } while (0)

#define MMA_M(bv, mh, nh) do {                                            \
    __builtin_amdgcn_s_setprio(1);                                        \
    _Pragma("unroll") for (int j = 0; j < 4; ++j)                         \
    _Pragma("unroll") for (int n = 0; n < 2; ++n)                         \
    _Pragma("unroll") for (int kk = 0; kk < 2; ++kk)                      \
        acc[(mh) * 4 + j][(nh) * 2 + n] =                                 \
            __builtin_amdgcn_mfma_f32_16x16x32_bf16(                      \
                a[j][kk], bv[n][kk], acc[(mh) * 4 + j][(nh) * 2 + n],     \
                0, 0, 0);                                                 \
    __builtin_amdgcn_s_setprio(0);                                        \
} while (0)

#define PRE_MFMA() do { __builtin_amdgcn_s_barrier();                     \
    asm volatile("s_waitcnt lgkmcnt(0)" ::: "memory");                    \
    __builtin_amdgcn_sched_barrier(0); } while (0)

    // ---- prologue ----
    STAGEH(Ap, m0, 0, As0, 0); STAGEH(Ap, m0, 0, As0, 1);
    STAGEH(Bp, n0, 0, Bs0, 0); STAGEH(Bp, n0, 0, Bs0, 1);
    STAGEH(Ap, m0, 1, As1, 0);
    asm volatile("s_waitcnt vmcnt(2)" ::: "memory");
    __builtin_amdgcn_s_barrier();
    __builtin_amdgcn_sched_barrier(0);

    const int niter = nkt >> 1;
    for (int it = 0; it < niter; ++it) {
        const int c1 = 2 * it + 1, c2 = 2 * it + 2, c3 = 2 * it + 3;
        const bool pf = (c2 < nkt);

        // P1
        LDA_M(As0, 0); LDB_M(b0, Bs0, 0);
        STAGEH(Ap, m0, c1, As1, 1);
        STAGEH(Bp, n0, c1, Bs1, 0);
        PRE_MFMA(); MMA_M(b0, 0, 0); __builtin_amdgcn_s_barrier();
        // P2
        LDB_M(b1, Bs0, 1);
        STAGEH(Bp, n0, c1, Bs1, 1);
        PRE_MFMA(); MMA_M(b1, 0, 1); __builtin_amdgcn_s_barrier();
        // P3
        LDA_M(As0, 1);
        if (pf) STAGEH(Bp, n0, c2, Bs0, 0);
        PRE_MFMA(); MMA_M(b1, 1, 1); __builtin_amdgcn_s_barrier();
        // P4
        if (pf) {
            STAGEH(Bp, n0, c2, Bs0, 1);
            asm volatile("s_waitcnt vmcnt(4)" ::: "memory");
        } else {
            asm volatile("s_waitcnt vmcnt(0)" ::: "memory");
        }
        __builtin_amdgcn_s_barrier();
        __builtin_amdgcn_sched_barrier(0);
        MMA_M(b0, 1, 0); __builtin_amdgcn_s_barrier();
        // P5
        LDA_M(As1, 0); LDB_M(b0, Bs1, 0);
        if (pf) STAGEH(Ap, m0, c2, As0, 0);
        PRE_MFMA(); MMA_M(b0, 0, 0); __builtin_amdgcn_s_barrier();
        // P6
        LDB_M(b1, Bs1, 1);
        if (pf) STAGEH(Ap, m0, c2, As0, 1);
        PRE_MFMA(); MMA_M(b1, 0, 1); __builtin_amdgcn_s_barrier();
        // P7
        LDA_M(As1, 1);
        PRE_MFMA(); MMA_M(b1, 1, 1); __builtin_amdgcn_s_barrier();
        // P8
        if (pf) {
            STAGEH(Ap, m0, c3, As1, 0);
            asm volatile("s_waitcnt vmcnt(2)" ::: "memory");
        }
        __builtin_amdgcn_s_barrier();
        __builtin_amdgcn_sched_barrier(0);
        MMA_M(b0, 1, 0); __builtin_amdgcn_s_barrier();
    }

    // ---- epilogue ----
#pragma unroll
    for (int fm = 0; fm < 8; ++fm) {
#pragma unroll
        for (int fn = 0; fn < 4; ++fn) {
            const long gcol = n0 + wn * 64 + fn * 16 + l16;
            float bv = 0.f;
            if (MODE != 0) bv = bias[gcol];
#pragma unroll
            for (int e = 0; e < 4; ++e) {
                const long grow = m0 + wm * 128 + fm * 16 + lg * 4 + e;
                float v = acc[fm][fn][e];
                if (MODE == 0) {
                    ((bf16_t*)outp)[grow * N + gcol] = (bf16_t)v;
                } else if (MODE == 1) {
                    v += bv + ((const float*)addp)[grow * N + gcol];
                    ((float*)outp)[grow * N + gcol] = v;
                } else if (MODE == 2) {
                    v += bv; v = v > 0.f ? v : 0.f;
                    ((bf16_t*)outp)[grow * N + gcol] = (bf16_t)v;
                } else {
                    v += bv + (float)((const bf16_t*)addp)[grow * N + gcol];
                    ((bf16_t*)outp)[grow * N + gcol] = (bf16_t)v;
                }
            }
        }
    }
#undef LDA_M
#undef LDB_M
#undef MMA_M
#undef PRE_MFMA
}

// ---------------- fused causal attention ----------------
__global__ __launch_bounds__(256)
void attn_kernel(const bf16_t* __restrict__ qkv, const bf16_t* __restrict__ vt,
                 bf16_t* __restrict__ outp)
{
    __shared__ __attribute__((aligned(16))) bf16_t Kt[64 * 64];
    __shared__ __attribute__((aligned(16))) bf16_t Vt[64 * 64];
    __shared__ __attribute__((aligned(16))) bf16_t Ps[4][16 * 72];

    const int tid = threadIdx.x, w = tid >> 6, lane = tid & 63;
    const int l16 = lane & 15, lg = lane >> 4;
    const int b = blockIdx.x >> 4, hh = blockIdx.x & 15;
    const bf16_t* pq = qkv + (long)(b * 256) * 3072 + hh * 64;
    const bf16_t* pv = vt + (long)blockIdx.x * 64 * 256;
    const int sr8 = lane >> 3;
    const int sl  = lane & 7;

    bf16x8 qf[4][2];
#pragma unroll
    for (int fm = 0; fm < 4; ++fm)
#pragma unroll
        for (int kk = 0; kk < 2; ++kk)
            qf[fm][kk] = *(const bf16x8*)(pq + (long)(w * 64 + fm * 16 + l16) * 3072
                                          + kk * 32 + lg * 8);

    f32x4 o[4][4] = {};
    float mrun[4][4], lrun[4][4];
#pragma unroll
    for (int i = 0; i < 4; ++i)
#pragma unroll
        for (int j = 0; j < 4; ++j) { mrun[i][j] = -__builtin_inff(); lrun[i][j] = 0.f; }

    for (int st = 0; st < 4; ++st) {
        __syncthreads();
#pragma unroll
        for (int i = 0; i < 2; ++i) {
            int r  = w * 16 + i * 8 + sr8;
            int ss = sl ^ (r & 7);
            gload_lds16(pq + (long)(st * 64 + r) * 3072 + 1024 + ss * 8,
                        &Kt[(w * 16 + i * 8) * 64]);
            gload_lds16(pv + (long)r * 256 + st * 64 + ss * 8,
                        &Vt[(w * 16 + i * 8) * 64]);
        }
        asm volatile("s_waitcnt vmcnt(0)" ::: "memory");
        __syncthreads();
        if (st > w) continue;

        f32x4 s[4][4] = {};
#pragma unroll
        for (int ks = 0; ks < 2; ++ks) {
            bf16x8 kb[4];
#pragma unroll
            for (int fs = 0; fs < 4; ++fs)
                kb[fs] = *(const bf16x8*)&Kt[(fs * 16 + l16) * 64
                                             + ((ks * 4 + lg) ^ (l16 & 7)) * 8];
#pragma unroll
            for (int fm = 0; fm < 4; ++fm)
#pragma unroll
                for (int fs = 0; fs < 4; ++fs)
                    s[fm][fs] = __builtin_amdgcn_mfma_f32_16x16x32_bf16(
                        qf[fm][ks], kb[fs], s[fm][fs], 0, 0, 0);
        }

#pragma unroll
        for (int fm = 0; fm < 4; ++fm) {
#pragma unroll
            for (int fs = 0; fs < 4; ++fs)
#pragma unroll
                for (int e = 0; e < 4; ++e) {
                    float v = s[fm][fs][e] * 0.03125f;
                    if (st == w && (fs * 16 + l16) > (fm * 16 + lg * 4 + e))
                        v = -__builtin_inff();
                    s[fm][fs][e] = v;
                }
#pragma unroll
            for (int e = 0; e < 4; ++e) {
                float pm = fmaxf(fmaxf(s[fm][0][e], s[fm][1][e]),
                                 fmaxf(s[fm][2][e], s[fm][3][e]));
#pragma unroll
                for (int off = 1; off < 16; off <<= 1) pm = fmaxf(pm, __shfl_xor(pm, off));
                float mnew  = fmaxf(mrun[fm][e], pm);
                float alpha = __expf(mrun[fm][e] - mnew);
                float rs = 0.f;
#pragma unroll
                for (int fs = 0; fs < 4; ++fs) {
                    float p = __expf(s[fm][fs][e] - mnew);
                    s[fm][fs][e] = p;
                    rs += p;
                }
#pragma unroll
                for (int off = 1; off < 16; off <<= 1) rs += __shfl_xor(rs, off);
                lrun[fm][e] = lrun[fm][e] * alpha + rs;
                mrun[fm][e] = mnew;
#pragma unroll
                for (int fd = 0; fd < 4; ++fd) o[fm][fd][e] *= alpha;
            }
#pragma unroll
            for (int fs = 0; fs < 4; ++fs)
#pragma unroll
                for (int e = 0; e < 4; ++e)
                    Ps[w][(lg * 4 + e) * 72 + fs * 16 + l16] = (bf16_t)s[fm][fs][e];
            bf16x8 ap0 = *(const bf16x8*)&Ps[w][l16 * 72 + lg * 8];
            bf16x8 ap1 = *(const bf16x8*)&Ps[w][l16 * 72 + 32 + lg * 8];
#pragma unroll
            for (int fd = 0; fd < 4; ++fd) {
                bf16x8 vb0 = *(const bf16x8*)&Vt[(fd * 16 + l16) * 64
                                                 + ((lg) ^ (l16 & 7)) * 8];
                bf16x8 vb1 = *(const bf16x8*)&Vt[(fd * 16 + l16) * 64
                                                 + ((4 + lg) ^ (l16 & 7)) * 8];
                o[fm][fd] = __builtin_amdgcn_mfma_f32_16x16x32_bf16(ap0, vb0, o[fm][fd], 0, 0, 0);
                o[fm][fd] = __builtin_amdgcn_mfma_f32_16x16x32_bf16(ap1, vb1, o[fm][fd], 0, 0, 0);
            }
        }
    }

#pragma unroll
    for (int fm = 0; fm < 4; ++fm)
#pragma unroll
        for (int e = 0; e < 4; ++e) {
            float inv = 1.f / lrun[fm][e];
            long row = (long)b * 256 + w * 64 + fm * 16 + lg * 4 + e;
#pragma unroll
            for (int fd = 0; fd < 4; ++fd)
                outp[row * 1024 + hh * 64 + fd * 16 + l16] =
                    (bf16_t)(o[fm][fd][e] * inv);
        }
}

// ---------------- launch ----------------
extern "C" void kernel_launch(void* const* d_in, const int* in_sizes, int n_in,
                              void* d_out, int out_size, void* d_ws, size_t ws_size,
                              hipStream_t stream)
{
    (void)in_sizes; (void)n_in; (void)out_size; (void)ws_size;
    const float* x      = (const float*)d_in[0];
    const float* wq     = (const float*)d_in[1];
    const float* wk     = (const float*)d_in[2];
    const float* wv     = (const float*)d_in[3];
    const float* w_proj = (const float*)d_in[4];
    const float* b_proj = (const float*)d_in[5];
    const float* w1     = (const float*)d_in[6];
    const float* b1     = (const float*)d_in[7];
    const float* w2     = (const float*)d_in[8];
    const float* b2     = (const float*)d_in[9];
    const float* g1  = (const float*)d_in[10]; const float* be1 = (const float*)d_in[11];
    const float* g2  = (const float*)d_in[12]; const float* be2 = (const float*)d_in[13];
    const float* g3  = (const float*)d_in[14]; const float* be3 = (const float*)d_in[15];

    char* ws = (char*)d_ws;
    // compact layout, total ~184 MiB:
    bf16_t* wqkv  = (bf16_t*)(ws + 0);           //  6,291,456
    bf16_t* wproj = (bf16_t*)(ws + 6291456);     //  2,097,152
    bf16_t* w1t   = (bf16_t*)(ws + 8388608);     //  8,388,608
    bf16_t* w2t   = (bf16_t*)(ws + 16777216);    //  8,388,608
    bf16_t* h     = (bf16_t*)(ws + 25165824);    // 33,554,432 (LN1 out; attn out; start of u)
    bf16_t* qkv   = (bf16_t*)(ws + 58720256);    // 100,663,296
    bf16_t* attn  = h;
    bf16_t* u     = h;                           // 134,217,728 over dead h+qkv
    bf16_t* y     = (bf16_t*)(ws + 159383552);   // 33,554,432 (vt before LN2; y after)
    bf16_t* vt    = y;                           // V^T lives here until proj GEMM done
    float*  x2    = (float*)d_out;
    bf16_t* tbuf  = y;

    const int M = 16384;

    // weight prep (LDS-tiled, coalesced)
    transpose_f32_bf16<<<dim3(16, 16), 256, 0, stream>>>(w_proj, wproj, 1024, 1024);
    transpose_f32_bf16<<<dim3(16, 64), 256, 0, stream>>>(w1, w1t, 4096, 1024);
    transpose_f32_bf16<<<dim3(64, 16), 256, 0, stream>>>(w2, w2t, 1024, 4096);
    pack_qkv_t<<<dim3(16, 48), 256, 0, stream>>>(wq, wk, wv, wqkv);

    // h = LN1(x)
    ln_fwd<<<M, 256, 0, stream>>>(x, g1, be1, h);
    // qkv = h @ Wqkv^T
    gemm_bt<0><<<dim3(64, 12), 512, 0, stream>>>(h, wqkv, qkv, nullptr, nullptr, M, 3072, 1024);
    // vt = V^T  (per (b,h): [64d][256s])
    v_transpose<<<8192, 256, 0, stream>>>(qkv, vt);
    // attention
    attn_kernel<<<1024, 256, 0, stream>>>(qkv, vt, attn);
    // x2 = x + attn @ Wproj^T + b_proj   -> d_out (f32)
    gemm_bt<1><<<dim3(64, 4), 512, 0, stream>>>(attn, wproj, x2, b_proj, x, M, 1024, 1024);
    // y = LN2(x2)   (overwrites vt, now dead)
    ln_fwd<<<M, 256, 0, stream>>>(x2, g2, be2, y);
    // u = relu(y @ W1^T + b1)
    gemm_bt<2><<<dim3(64, 16), 512, 0, stream>>>(y, w1t, u, b1, nullptr, M, 4096, 1024);
    // tbuf = y + (u @ W2^T + b2)  (bf16, in-place over y)
    gemm_bt<3><<<dim3(64, 4), 512, 0, stream>>>(u, w2t, tbuf, b2, y, M, 1024, 4096);
    // d_out = x2 + LN3(tbuf)
    ln3_kernel<<<M, 256, 0, stream>>>(tbuf, g3, be3, (float*)d_out, x2);
}

// Round 11
// 655.352 us; speedup vs baseline: 1.4916x; 1.0397x over previous
//
#include <hip/hip_runtime.h>

typedef __bf16 bf16_t;
typedef __bf16 bf16x8 __attribute__((ext_vector_type(8)));
typedef float f32x4 __attribute__((ext_vector_type(4)));

#define LN_EPS 1e-3f

__device__ __forceinline__ void gload_lds16(const void* g, void* l) {
    __builtin_amdgcn_global_load_lds(
        (__attribute__((address_space(1))) void*)(g),
        (__attribute__((address_space(3))) void*)(l), 16, 0, 0);
}

// ---------------- weight prep (LDS-tiled, coalesced both sides) ----------------
__global__ __launch_bounds__(256)
void transpose_f32_bf16(const float* __restrict__ in, bf16_t* __restrict__ outp,
                        int ldi, int ldo)
{
    __shared__ float tile[64][65];
    const int k0 = blockIdx.x * 64, n0 = blockIdx.y * 64;
    const int tid = threadIdx.x;
    const int r = tid >> 2;
    const int q = tid & 3;
    const float* src = in + (long)(k0 + r) * ldi + n0 + q * 16;
#pragma unroll
    for (int j = 0; j < 4; ++j) {
        float4 v = *(const float4*)(src + j * 4);
        tile[r][q * 16 + j * 4 + 0] = v.x;
        tile[r][q * 16 + j * 4 + 1] = v.y;
        tile[r][q * 16 + j * 4 + 2] = v.z;
        tile[r][q * 16 + j * 4 + 3] = v.w;
    }
    __syncthreads();
    union { bf16_t e[16]; uint4 u[2]; } pk;
#pragma unroll
    for (int j = 0; j < 16; ++j) pk.e[j] = (bf16_t)tile[q * 16 + j][r];
    bf16_t* dst = outp + (long)(n0 + r) * ldo + k0 + q * 16;
    *(uint4*)(dst)     = pk.u[0];
    *(uint4*)(dst + 8) = pk.u[1];
}

__global__ __launch_bounds__(256)
void pack_qkv_t(const float* __restrict__ wq, const float* __restrict__ wk,
                const float* __restrict__ wv, bf16_t* __restrict__ outp)
{
    __shared__ float tile[64][65];
    const int m   = blockIdx.y;           // 0..47
    const int sel = m >> 4, h = m & 15;
    const float* in = ((sel == 0) ? wq : (sel == 1) ? wk : wv) + (long)h * 65536;
    bf16_t* out = outp + ((long)sel * 1024 + h * 64) * 1024;
    const int k0 = blockIdx.x * 64;
    const int tid = threadIdx.x;
    const int r = tid >> 2;
    const int q = tid & 3;
    const float* src = in + (long)(k0 + r) * 64 + q * 16;
#pragma unroll
    for (int j = 0; j < 4; ++j) {
        float4 v = *(const float4*)(src + j * 4);
        tile[r][q * 16 + j * 4 + 0] = v.x;
        tile[r][q * 16 + j * 4 + 1] = v.y;
        tile[r][q * 16 + j * 4 + 2] = v.z;
        tile[r][q * 16 + j * 4 + 3] = v.w;
    }
    __syncthreads();
    union { bf16_t e[16]; uint4 u[2]; } pk;
#pragma unroll
    for (int j = 0; j < 16; ++j) pk.e[j] = (bf16_t)tile[q * 16 + j][r];
    bf16_t* dst = out + (long)r * 1024 + k0 + q * 16;
    *(uint4*)(dst)     = pk.u[0];
    *(uint4*)(dst + 8) = pk.u[1];
}

// vt[(b*16+h)*64 + d][s] = v[b*256+s][h*64+d]
__global__ __launch_bounds__(256)
void v_transpose(const bf16_t* __restrict__ qkv, bf16_t* __restrict__ vt)
{
    int g  = blockIdx.x * 256 + threadIdx.x;
    int bh = g >> 11;
    int r  = g & 2047;
    int d  = r & 63;
    int sg = r >> 6;
    int b  = bh >> 4, h = bh & 15;
    const bf16_t* src = qkv + ((long)b * 256 + sg * 8) * 3072 + 2048 + h * 64 + d;
    union { bf16_t e[8]; uint4 u; } pk;
#pragma unroll
    for (int e = 0; e < 8; ++e) pk.e[e] = src[(long)e * 3072];
    *(uint4*)(vt + ((long)bh * 64 + d) * 256 + sg * 8) = pk.u;
}

// ---------------- layernorm (f32 in -> bf16 LN out) ----------------
__global__ __launch_bounds__(256)
void ln_fwd(const float* __restrict__ in, const float* __restrict__ g,
            const float* __restrict__ be, bf16_t* __restrict__ outp)
{
    const long row = blockIdx.x;
    const int t = threadIdx.x;
    float4 v = ((const float4*)(in + row * 1024))[t];
    float s  = v.x + v.y + v.z + v.w;
    float sq = v.x * v.x + v.y * v.y + v.z * v.z + v.w * v.w;
#pragma unroll
    for (int off = 1; off < 64; off <<= 1) {
        s  += __shfl_xor(s, off);
        sq += __shfl_xor(sq, off);
    }
    __shared__ float red[8];
    if ((t & 63) == 0) { red[(t >> 6) * 2] = s; red[(t >> 6) * 2 + 1] = sq; }
    __syncthreads();
    s  = red[0] + red[2] + red[4] + red[6];
    sq = red[1] + red[3] + red[5] + red[7];
    float mean = s * 0.0009765625f;
    float var  = sq * 0.0009765625f - mean * mean;
    float rstd = rsqrtf(var + LN_EPS);
    float4 gv = ((const float4*)g)[t];
    float4 bv = ((const float4*)be)[t];
    union { bf16_t h[4]; uint2 u; } pk;
    pk.h[0] = (bf16_t)((v.x - mean) * rstd * gv.x + bv.x);
    pk.h[1] = (bf16_t)((v.y - mean) * rstd * gv.y + bv.y);
    pk.h[2] = (bf16_t)((v.z - mean) * rstd * gv.z + bv.z);
    pk.h[3] = (bf16_t)((v.w - mean) * rstd * gv.w + bv.w);
    *(uint2*)(outp + row * 1024 + t * 4) = pk.u;
}

// ---------------- final layernorm (bf16 in + f32 res -> f32 out) ----------------
__global__ __launch_bounds__(256)
void ln3_kernel(const bf16_t* __restrict__ in, const float* __restrict__ g,
                const float* __restrict__ be, float* outp, const float* res)
{
    const long row = blockIdx.x;
    const int t = threadIdx.x;
    union { uint2 u; bf16_t h[4]; } pk;
    pk.u = *(const uint2*)(in + row * 1024 + t * 4);
    float v0 = (float)pk.h[0], v1 = (float)pk.h[1], v2 = (float)pk.h[2], v3 = (float)pk.h[3];
    float s  = v0 + v1 + v2 + v3;
    float sq = v0 * v0 + v1 * v1 + v2 * v2 + v3 * v3;
#pragma unroll
    for (int off = 1; off < 64; off <<= 1) {
        s  += __shfl_xor(s, off);
        sq += __shfl_xor(sq, off);
    }
    __shared__ float red[8];
    if ((t & 63) == 0) { red[(t >> 6) * 2] = s; red[(t >> 6) * 2 + 1] = sq; }
    __syncthreads();
    s  = red[0] + red[2] + red[4] + red[6];
    sq = red[1] + red[3] + red[5] + red[7];
    float mean = s * 0.0009765625f;
    float var  = sq * 0.0009765625f - mean * mean;
    float rstd = rsqrtf(var + LN_EPS);
    float4 gv = ((const float4*)g)[t];
    float4 bv = ((const float4*)be)[t];
    float4 rv = ((const float4*)(res + row * 1024))[t];
    float4 ov;
    ov.x = rv.x + (v0 - mean) * rstd * gv.x + bv.x;
    ov.y = rv.y + (v1 - mean) * rstd * gv.y + bv.y;
    ov.z = rv.z + (v2 - mean) * rstd * gv.z + bv.z;
    ov.w = rv.w + (v3 - mean) * rstd * gv.w + bv.w;
    ((float4*)outp)[row * 256 + t] = ov;
}

// ---------------- GEMM: C[M,N] = A[M,K] * Bt[N,K]^T ----------------
// 256x256 tile, BK=64, 512 threads = 8 waves; 4 phases per K-tile.
// Deep pipeline: A (HBM-streamed) has 3 LDS buffers, staged 2 K-tiles ahead
// (6-8 phase cover ~ 1000-1300cy > 900cy HBM latency); B (L2-hot weights) has
// 2 buffers, staged 1 tile ahead at P1 (3-phase cover ~ 480cy > L2 latency).
// LDS = 5 x 32KB = 160KB (HW max, 1 block/CU).
// Ledger per iter c (steady state):
//   P1: ds LDA(Ar,h0)+LDB(b0,Br,0); stage B(c+1)h0,h1 -> Bw; A(c+2)h0 -> An2; MMA(0,0)
//   P2: ds LDB(b1,Br,1); MMA(0,1)
//   P3: ds LDA(Ar,h1); stage A(c+2)h1 -> An2; MMA(1,1)
//   P4: vmcnt(4) [queue: A(c+1)h1|B(c+1)h0|B(c+1)h1|A(c+2)h0|A(c+2)h1 (10) ->
//       drains first 6, leaves A(c+2)]; barrier; MMA(1,0)
// Write-after-read: An2 = buffer read in iter c-1 (done by c-1.P3 barrier);
// Bw = buffer read in iter c-1 P1/P2. Landing: A(c),B(c) forced by c-1.P4 wait.
// MODE 0: bf16=acc; 1: f32=acc+bias+addf32; 2: bf16=relu(acc+bias);
// MODE 3: bf16=acc+bias+(float)addbf16 (outp may == addp)
template<int MODE>
__global__ __launch_bounds__(512, 2)
void gemm_bt(const bf16_t* __restrict__ Ap, const bf16_t* __restrict__ Bp,
             void* outp, const float* __restrict__ bias,
             const void* addp, int M, int N, int K)
{
    __shared__ __attribute__((aligned(16))) bf16_t As0[256 * 64];
    __shared__ __attribute__((aligned(16))) bf16_t As1[256 * 64];
    __shared__ __attribute__((aligned(16))) bf16_t As2[256 * 64];
    __shared__ __attribute__((aligned(16))) bf16_t Bs0[256 * 64];
    __shared__ __attribute__((aligned(16))) bf16_t Bs1[256 * 64];

    const int tid  = threadIdx.x;
    const int w    = tid >> 6, lane = tid & 63;
    const int l16  = lane & 15, lg = lane >> 4;
    const int wm   = w >> 2, wn = w & 3;
    const int srow = lane >> 3;
    const int sslot = lane & 7;

    const int gx  = gridDim.x;
    const int gy  = gridDim.y;
    const int nwg = gx * gy;
    const int bid = blockIdx.y * gx + blockIdx.x;
    const int cpx = nwg >> 3;
    const int sid = (bid & 7) * cpx + (bid >> 3);
    const long m0 = (long)(sid / gy) * 256;
    const long n0 = (long)(sid % gy) * 256;
    const int nkt = K >> 6;

    f32x4 acc[8][4] = {};
    bf16x8 a[4][2], b0[2][2], b1[2][2];

    auto STAGEH = [&](const bf16_t* src, long row0, int kt, bf16_t* dst, int h) {
#pragma unroll
        for (int i = 0; i < 2; ++i) {
            int r  = h * 128 + w * 16 + i * 8 + srow;
            int ss = sslot ^ (r & 7);
            gload_lds16(src + (row0 + r) * (long)K + (long)kt * 64 + ss * 8,
                        dst + (h * 128 + w * 16 + i * 8) * 64);
        }
    };

#define LDA_M(buf, mh) do {                                               \
    _Pragma("unroll") for (int j = 0; j < 4; ++j)                         \
    _Pragma("unroll") for (int kk = 0; kk < 2; ++kk) {                    \
        int r  = wm * 128 + (mh) * 64 + j * 16 + l16;                     \
        int ss = (kk * 4 + lg) ^ (r & 7);                                 \
        a[j][kk] = *(const bf16x8*)&buf[r * 64 + ss * 8];                 \
    } } while (0)

#define LDB_M(dst, buf, nh) do {                                          \
    _Pragma("unroll") for (int n = 0; n < 2; ++n)                         \
    _Pragma("unroll") for (int kk = 0; kk < 2; ++kk) {                    \
        int r  = wn * 64 + ((nh) * 2 + n) * 16 + l16;                     \
        int ss = (kk * 4 + lg) ^ (r & 7);                                 \
        dst[n][kk] = *(const bf16x8*)&buf[r * 64 + ss * 8];               \
    } } while (0)

#define MMA_M(bv, mh, nh) do {                                            \
    __builtin_amdgcn_s_setprio(1);                                        \
    _Pragma("unroll") for (int j = 0; j < 4; ++j)                         \
    _Pragma("unroll") for (int n = 0; n < 2; ++n)                         \
    _Pragma("unroll") for (int kk = 0; kk < 2; ++kk)                      \
        acc[(mh) * 4 + j][(nh) * 2 + n] =                                 \
            __builtin_amdgcn_mfma_f32_16x16x32_bf16(                      \
                a[j][kk], bv[n][kk], acc[(mh) * 4 + j][(nh) * 2 + n],     \
                0, 0, 0);                                                 \
    __builtin_amdgcn_s_setprio(0);                                        \
} while (0)

#define PRE_MFMA() do { __builtin_amdgcn_s_barrier();                     \
    asm volatile("s_waitcnt lgkmcnt(0)" ::: "memory");                    \
    __builtin_amdgcn_sched_barrier(0); } while (0)

    // ---- prologue: A(0)->As0, B(0)->Bs0, A(1)->As1, all landed ----
    STAGEH(Ap, m0, 0, As0, 0); STAGEH(Ap, m0, 0, As0, 1);
    STAGEH(Bp, n0, 0, Bs0, 0); STAGEH(Bp, n0, 0, Bs0, 1);
    STAGEH(Ap, m0, 1, As1, 0); STAGEH(Ap, m0, 1, As1, 1);
    asm volatile("s_waitcnt vmcnt(0)" ::: "memory");
    __builtin_amdgcn_s_barrier();
    __builtin_amdgcn_sched_barrier(0);

    bf16_t *Ar = As0, *An1 = As1, *An2 = As2;
    bf16_t *Br = Bs0, *Bw = Bs1;

    for (int c = 0; c < nkt; ++c) {
        const bool pfa = (c + 2 < nkt);
        const bool pfb = (c + 1 < nkt);

        // P1
        LDA_M(Ar, 0); LDB_M(b0, Br, 0);
        if (pfb) { STAGEH(Bp, n0, c + 1, Bw, 0); STAGEH(Bp, n0, c + 1, Bw, 1); }
        if (pfa) STAGEH(Ap, m0, c + 2, An2, 0);
        PRE_MFMA(); MMA_M(b0, 0, 0); __builtin_amdgcn_s_barrier();
        // P2
        LDB_M(b1, Br, 1);
        PRE_MFMA(); MMA_M(b1, 0, 1); __builtin_amdgcn_s_barrier();
        // P3
        LDA_M(Ar, 1);
        if (pfa) STAGEH(Ap, m0, c + 2, An2, 1);
        PRE_MFMA(); MMA_M(b1, 1, 1); __builtin_amdgcn_s_barrier();
        // P4
        if (pfa) { asm volatile("s_waitcnt vmcnt(4)" ::: "memory"); }
        else     { asm volatile("s_waitcnt vmcnt(0)" ::: "memory"); }
        __builtin_amdgcn_s_barrier();
        __builtin_amdgcn_sched_barrier(0);
        MMA_M(b0, 1, 0); __builtin_amdgcn_s_barrier();

        // rotate buffers
        bf16_t* t = Ar; Ar = An1; An1 = An2; An2 = t;
        t = Br; Br = Bw; Bw = t;
    }

    // ---- epilogue ----
#pragma unroll
    for (int fm = 0; fm < 8; ++fm) {
#pragma unroll
        for (int fn = 0; fn < 4; ++fn) {
            const long gcol = n0 + wn * 64 + fn * 16 + l16;
            float bv = 0.f;
            if (MODE != 0) bv = bias[gcol];
#pragma unroll
            for (int e = 0; e < 4; ++e) {
                const long grow = m0 + wm * 128 + fm * 16 + lg * 4 + e;
                float v = acc[fm][fn][e];
                if (MODE == 0) {
                    ((bf16_t*)outp)[grow * N + gcol] = (bf16_t)v;
                } else if (MODE == 1) {
                    v += bv + ((const float*)addp)[grow * N + gcol];
                    ((float*)outp)[grow * N + gcol] = v;
                } else if (MODE == 2) {
                    v += bv; v = v > 0.f ? v : 0.f;
                    ((bf16_t*)outp)[grow * N + gcol] = (bf16_t)v;
                } else {
                    v += bv + (float)((const bf16_t*)addp)[grow * N + gcol];
                    ((bf16_t*)outp)[grow * N + gcol] = (bf16_t)v;
                }
            }
        }
    }
#undef LDA_M
#undef LDB_M
#undef MMA_M
#undef PRE_MFMA
}

// ---------------- fused causal attention ----------------
__global__ __launch_bounds__(256)
void attn_kernel(const bf16_t* __restrict__ qkv, const bf16_t* __restrict__ vt,
                 bf16_t* __restrict__ outp)
{
    __shared__ __attribute__((aligned(16))) bf16_t Kt[64 * 64];
    __shared__ __attribute__((aligned(16))) bf16_t Vt[64 * 64];
    __shared__ __attribute__((aligned(16))) bf16_t Ps[4][16 * 72];

    const int tid = threadIdx.x, w = tid >> 6, lane = tid & 63;
    const int l16 = lane & 15, lg = lane >> 4;
    const int b = blockIdx.x >> 4, hh = blockIdx.x & 15;
    const bf16_t* pq = qkv + (long)(b * 256) * 3072 + hh * 64;
    const bf16_t* pv = vt + (long)blockIdx.x * 64 * 256;
    const int sr8 = lane >> 3;
    const int sl  = lane & 7;

    bf16x8 qf[4][2];
#pragma unroll
    for (int fm = 0; fm < 4; ++fm)
#pragma unroll
        for (int kk = 0; kk < 2; ++kk)
            qf[fm][kk] = *(const bf16x8*)(pq + (long)(w * 64 + fm * 16 + l16) * 3072
                                          + kk * 32 + lg * 8);

    f32x4 o[4][4] = {};
    float mrun[4][4], lrun[4][4];
#pragma unroll
    for (int i = 0; i < 4; ++i)
#pragma unroll
        for (int j = 0; j < 4; ++j) { mrun[i][j] = -__builtin_inff(); lrun[i][j] = 0.f; }

    for (int st = 0; st < 4; ++st) {
        __syncthreads();
#pragma unroll
        for (int i = 0; i < 2; ++i) {
            int r  = w * 16 + i * 8 + sr8;
            int ss = sl ^ (r & 7);
            gload_lds16(pq + (long)(st * 64 + r) * 3072 + 1024 + ss * 8,
                        &Kt[(w * 16 + i * 8) * 64]);
            gload_lds16(pv + (long)r * 256 + st * 64 + ss * 8,
                        &Vt[(w * 16 + i * 8) * 64]);
        }
        asm volatile("s_waitcnt vmcnt(0)" ::: "memory");
        __syncthreads();
        if (st > w) continue;

        f32x4 s[4][4] = {};
#pragma unroll
        for (int ks = 0; ks < 2; ++ks) {
            bf16x8 kb[4];
#pragma unroll
            for (int fs = 0; fs < 4; ++fs)
                kb[fs] = *(const bf16x8*)&Kt[(fs * 16 + l16) * 64
                                             + ((ks * 4 + lg) ^ (l16 & 7)) * 8];
#pragma unroll
            for (int fm = 0; fm < 4; ++fm)
#pragma unroll
                for (int fs = 0; fs < 4; ++fs)
                    s[fm][fs] = __builtin_amdgcn_mfma_f32_16x16x32_bf16(
                        qf[fm][ks], kb[fs], s[fm][fs], 0, 0, 0);
        }

#pragma unroll
        for (int fm = 0; fm < 4; ++fm) {
#pragma unroll
            for (int fs = 0; fs < 4; ++fs)
#pragma unroll
                for (int e = 0; e < 4; ++e) {
                    float v = s[fm][fs][e] * 0.03125f;
                    if (st == w && (fs * 16 + l16) > (fm * 16 + lg * 4 + e))
                        v = -__builtin_inff();
                    s[fm][fs][e] = v;
                }
#pragma unroll
            for (int e = 0; e < 4; ++e) {
                float pm = fmaxf(fmaxf(s[fm][0][e], s[fm][1][e]),
                                 fmaxf(s[fm][2][e], s[fm][3][e]));
#pragma unroll
                for (int off = 1; off < 16; off <<= 1) pm = fmaxf(pm, __shfl_xor(pm, off));
                float mnew  = fmaxf(mrun[fm][e], pm);
                float alpha = __expf(mrun[fm][e] - mnew);
                float rs = 0.f;
#pragma unroll
                for (int fs = 0; fs < 4; ++fs) {
                    float p = __expf(s[fm][fs][e] - mnew);
                    s[fm][fs][e] = p;
                    rs += p;
                }
#pragma unroll
                for (int off = 1; off < 16; off <<= 1) rs += __shfl_xor(rs, off);
                lrun[fm][e] = lrun[fm][e] * alpha + rs;
                mrun[fm][e] = mnew;
#pragma unroll
                for (int fd = 0; fd < 4; ++fd) o[fm][fd][e] *= alpha;
            }
#pragma unroll
            for (int fs = 0; fs < 4; ++fs)
#pragma unroll
                for (int e = 0; e < 4; ++e)
                    Ps[w][(lg * 4 + e) * 72 + fs * 16 + l16] = (bf16_t)s[fm][fs][e];
            bf16x8 ap0 = *(const bf16x8*)&Ps[w][l16 * 72 + lg * 8];
            bf16x8 ap1 = *(const bf16x8*)&Ps[w][l16 * 72 + 32 + lg * 8];
#pragma unroll
            for (int fd = 0; fd < 4; ++fd) {
                bf16x8 vb0 = *(const bf16x8*)&Vt[(fd * 16 + l16) * 64
                                                 + ((lg) ^ (l16 & 7)) * 8];
                bf16x8 vb1 = *(const bf16x8*)&Vt[(fd * 16 + l16) * 64
                                                 + ((4 + lg) ^ (l16 & 7)) * 8];
                o[fm][fd] = __builtin_amdgcn_mfma_f32_16x16x32_bf16(ap0, vb0, o[fm][fd], 0, 0, 0);
                o[fm][fd] = __builtin_amdgcn_mfma_f32_16x16x32_bf16(ap1, vb1, o[fm][fd], 0, 0, 0);
            }
        }
    }

#pragma unroll
    for (int fm = 0; fm < 4; ++fm)
#pragma unroll
        for (int e = 0; e < 4; ++e) {
            float inv = 1.f / lrun[fm][e];
            long row = (long)b * 256 + w * 64 + fm * 16 + lg * 4 + e;
#pragma unroll
            for (int fd = 0; fd < 4; ++fd)
                outp[row * 1024 + hh * 64 + fd * 16 + l16] =
                    (bf16_t)(o[fm][fd][e] * inv);
        }
}

// ---------------- launch ----------------
extern "C" void kernel_launch(void* const* d_in, const int* in_sizes, int n_in,
                              void* d_out, int out_size, void* d_ws, size_t ws_size,
                              hipStream_t stream)
{
    (void)in_sizes; (void)n_in; (void)out_size; (void)ws_size;
    const float* x      = (const float*)d_in[0];
    const float* wq     = (const float*)d_in[1];
    const float* wk     = (const float*)d_in[2];
    const float* wv     = (const float*)d_in[3];
    const float* w_proj = (const float*)d_in[4];
    const float* b_proj = (const float*)d_in[5];
    const float* w1     = (const float*)d_in[6];
    const float* b1     = (const float*)d_in[7];
    const float* w2     = (const float*)d_in[8];
    const float* b2     = (const float*)d_in[9];
    const float* g1  = (const float*)d_in[10]; const float* be1 = (const float*)d_in[11];
    const float* g2  = (const float*)d_in[12]; const float* be2 = (const float*)d_in[13];
    const float* g3  = (const float*)d_in[14]; const float* be3 = (const float*)d_in[15];

    char* ws = (char*)d_ws;
    bf16_t* wqkv  = (bf16_t*)(ws + 0);           //  6,291,456
    bf16_t* wproj = (bf16_t*)(ws + 6291456);     //  2,097,152
    bf16_t* w1t   = (bf16_t*)(ws + 8388608);     //  8,388,608
    bf16_t* w2t   = (bf16_t*)(ws + 16777216);    //  8,388,608
    bf16_t* h     = (bf16_t*)(ws + 25165824);    // 33,554,432 (LN1 out; attn out; start of u)
    bf16_t* qkv   = (bf16_t*)(ws + 58720256);    // 100,663,296
    bf16_t* attn  = h;
    bf16_t* u     = h;                           // 134,217,728 over dead h+qkv
    bf16_t* y     = (bf16_t*)(ws + 159383552);   // 33,554,432 (vt before LN2; y after)
    bf16_t* vt    = y;
    float*  x2    = (float*)d_out;
    bf16_t* tbuf  = y;

    const int M = 16384;

    transpose_f32_bf16<<<dim3(16, 16), 256, 0, stream>>>(w_proj, wproj, 1024, 1024);
    transpose_f32_bf16<<<dim3(16, 64), 256, 0, stream>>>(w1, w1t, 4096, 1024);
    transpose_f32_bf16<<<dim3(64, 16), 256, 0, stream>>>(w2, w2t, 1024, 4096);
    pack_qkv_t<<<dim3(16, 48), 256, 0, stream>>>(wq, wk, wv, wqkv);

    // h = LN1(x)
    ln_fwd<<<M, 256, 0, stream>>>(x, g1, be1, h);
    // qkv = h @ Wqkv^T
    gemm_bt<0><<<dim3(64, 12), 512, 0, stream>>>(h, wqkv, qkv, nullptr, nullptr, M, 3072, 1024);
    // vt = V^T
    v_transpose<<<8192, 256, 0, stream>>>(qkv, vt);
    // attention
    attn_kernel<<<1024, 256, 0, stream>>>(qkv, vt, attn);
    // x2 = x + attn @ Wproj^T + b_proj   -> d_out (f32)
    gemm_bt<1><<<dim3(64, 4), 512, 0, stream>>>(attn, wproj, x2, b_proj, x, M, 1024, 1024);
    // y = LN2(x2)
    ln_fwd<<<M, 256, 0, stream>>>(x2, g2, be2, y);
    // u = relu(y @ W1^T + b1)
    gemm_bt<2><<<dim3(64, 16), 512, 0, stream>>>(y, w1t, u, b1, nullptr, M, 4096, 1024);
    // tbuf = y + (u @ W2^T + b2)
    gemm_bt<3><<<dim3(64, 4), 512, 0, stream>>>(u, w2t, tbuf, b2, y, M, 1024, 4096);
    // d_out = x2 + LN3(tbuf)
    ln3_kernel<<<M, 256, 0, stream>>>(tbuf, g3, be3, (float*)d_out, x2);
}

// Round 12
// 634.592 us; speedup vs baseline: 1.5404x; 1.0327x over previous
//
#include <hip/hip_runtime.h>

typedef __bf16 bf16_t;
typedef __bf16 bf16x8 __attribute__((ext_vector_type(8)));
typedef float f32x4 __attribute__((ext_vector_type(4)));

#define LN_EPS 1e-3f

__device__ __forceinline__ void gload_lds16(const void* g, void* l) {
    __builtin_amdgcn_global_load_lds(
        (__attribute__((address_space(1))) void*)(g),
        (__attribute__((address_space(3))) void*)(l), 16, 0, 0);
}

// ---------------- weight prep (LDS-tiled, coalesced both sides) ----------------
__global__ __launch_bounds__(256)
void transpose_f32_bf16(const float* __restrict__ in, bf16_t* __restrict__ outp,
                        int ldi, int ldo)
{
    __shared__ float tile[64][65];
    const int k0 = blockIdx.x * 64, n0 = blockIdx.y * 64;
    const int tid = threadIdx.x;
    const int r = tid >> 2;
    const int q = tid & 3;
    const float* src = in + (long)(k0 + r) * ldi + n0 + q * 16;
#pragma unroll
    for (int j = 0; j < 4; ++j) {
        float4 v = *(const float4*)(src + j * 4);
        tile[r][q * 16 + j * 4 + 0] = v.x;
        tile[r][q * 16 + j * 4 + 1] = v.y;
        tile[r][q * 16 + j * 4 + 2] = v.z;
        tile[r][q * 16 + j * 4 + 3] = v.w;
    }
    __syncthreads();
    union { bf16_t e[16]; uint4 u[2]; } pk;
#pragma unroll
    for (int j = 0; j < 16; ++j) pk.e[j] = (bf16_t)tile[q * 16 + j][r];
    bf16_t* dst = outp + (long)(n0 + r) * ldo + k0 + q * 16;
    *(uint4*)(dst)     = pk.u[0];
    *(uint4*)(dst + 8) = pk.u[1];
}

__global__ __launch_bounds__(256)
void pack_qkv_t(const float* __restrict__ wq, const float* __restrict__ wk,
                const float* __restrict__ wv, bf16_t* __restrict__ outp)
{
    __shared__ float tile[64][65];
    const int m   = blockIdx.y;           // 0..47
    const int sel = m >> 4, h = m & 15;
    const float* in = ((sel == 0) ? wq : (sel == 1) ? wk : wv) + (long)h * 65536;
    bf16_t* out = outp + ((long)sel * 1024 + h * 64) * 1024;
    const int k0 = blockIdx.x * 64;
    const int tid = threadIdx.x;
    const int r = tid >> 2;
    const int q = tid & 3;
    const float* src = in + (long)(k0 + r) * 64 + q * 16;
#pragma unroll
    for (int j = 0; j < 4; ++j) {
        float4 v = *(const float4*)(src + j * 4);
        tile[r][q * 16 + j * 4 + 0] = v.x;
        tile[r][q * 16 + j * 4 + 1] = v.y;
        tile[r][q * 16 + j * 4 + 2] = v.z;
        tile[r][q * 16 + j * 4 + 3] = v.w;
    }
    __syncthreads();
    union { bf16_t e[16]; uint4 u[2]; } pk;
#pragma unroll
    for (int j = 0; j < 16; ++j) pk.e[j] = (bf16_t)tile[q * 16 + j][r];
    bf16_t* dst = out + (long)r * 1024 + k0 + q * 16;
    *(uint4*)(dst)     = pk.u[0];
    *(uint4*)(dst + 8) = pk.u[1];
}

// ---------------- layernorm (f32 in -> bf16 LN out) ----------------
__global__ __launch_bounds__(256)
void ln_fwd(const float* __restrict__ in, const float* __restrict__ g,
            const float* __restrict__ be, bf16_t* __restrict__ outp)
{
    const long row = blockIdx.x;
    const int t = threadIdx.x;
    float4 v = ((const float4*)(in + row * 1024))[t];
    float s  = v.x + v.y + v.z + v.w;
    float sq = v.x * v.x + v.y * v.y + v.z * v.z + v.w * v.w;
#pragma unroll
    for (int off = 1; off < 64; off <<= 1) {
        s  += __shfl_xor(s, off);
        sq += __shfl_xor(sq, off);
    }
    __shared__ float red[8];
    if ((t & 63) == 0) { red[(t >> 6) * 2] = s; red[(t >> 6) * 2 + 1] = sq; }
    __syncthreads();
    s  = red[0] + red[2] + red[4] + red[6];
    sq = red[1] + red[3] + red[5] + red[7];
    float mean = s * 0.0009765625f;
    float var  = sq * 0.0009765625f - mean * mean;
    float rstd = rsqrtf(var + LN_EPS);
    float4 gv = ((const float4*)g)[t];
    float4 bv = ((const float4*)be)[t];
    union { bf16_t h[4]; uint2 u; } pk;
    pk.h[0] = (bf16_t)((v.x - mean) * rstd * gv.x + bv.x);
    pk.h[1] = (bf16_t)((v.y - mean) * rstd * gv.y + bv.y);
    pk.h[2] = (bf16_t)((v.z - mean) * rstd * gv.z + bv.z);
    pk.h[3] = (bf16_t)((v.w - mean) * rstd * gv.w + bv.w);
    *(uint2*)(outp + row * 1024 + t * 4) = pk.u;
}

// ---------------- final layernorm (bf16 in + f32 res -> f32 out) ----------------
__global__ __launch_bounds__(256)
void ln3_kernel(const bf16_t* __restrict__ in, const float* __restrict__ g,
                const float* __restrict__ be, float* outp, const float* res)
{
    const long row = blockIdx.x;
    const int t = threadIdx.x;
    union { uint2 u; bf16_t h[4]; } pk;
    pk.u = *(const uint2*)(in + row * 1024 + t * 4);
    float v0 = (float)pk.h[0], v1 = (float)pk.h[1], v2 = (float)pk.h[2], v3 = (float)pk.h[3];
    float s  = v0 + v1 + v2 + v3;
    float sq = v0 * v0 + v1 * v1 + v2 * v2 + v3 * v3;
#pragma unroll
    for (int off = 1; off < 64; off <<= 1) {
        s  += __shfl_xor(s, off);
        sq += __shfl_xor(sq, off);
    }
    __shared__ float red[8];
    if ((t & 63) == 0) { red[(t >> 6) * 2] = s; red[(t >> 6) * 2 + 1] = sq; }
    __syncthreads();
    s  = red[0] + red[2] + red[4] + red[6];
    sq = red[1] + red[3] + red[5] + red[7];
    float mean = s * 0.0009765625f;
    float var  = sq * 0.0009765625f - mean * mean;
    float rstd = rsqrtf(var + LN_EPS);
    float4 gv = ((const float4*)g)[t];
    float4 bv = ((const float4*)be)[t];
    float4 rv = ((const float4*)(res + row * 1024))[t];
    float4 ov;
    ov.x = rv.x + (v0 - mean) * rstd * gv.x + bv.x;
    ov.y = rv.y + (v1 - mean) * rstd * gv.y + bv.y;
    ov.z = rv.z + (v2 - mean) * rstd * gv.z + bv.z;
    ov.w = rv.w + (v3 - mean) * rstd * gv.w + bv.w;
    ((float4*)outp)[row * 256 + t] = ov;
}

// ---------------- GEMM: C[M,N] = A[M,K] * Bt[N,K]^T ----------------
// 256x256 tile, BK=64, 512 threads = 8 waves; 4 phases/K-tile; A 3-buf staged
// 2 tiles ahead, B 2-buf staged 1 tile ahead; LDS 160KB. Ledger: see r11.
// MODE 0: bf16=acc; 1: f32=acc+bias+addf32; 2: bf16=relu(acc+bias);
// MODE 3: bf16=acc+bias+(float)addbf16 (outp may == addp);
// MODE 4: QKV mode — cols<2048 bf16=acc to outp; cols>=2048 (V) write V^T into
//         addp as vt[((b*16+h)*64+d)*256 + s] (packed 4-row uint2 stores).
template<int MODE>
__global__ __launch_bounds__(512, 2)
void gemm_bt(const bf16_t* __restrict__ Ap, const bf16_t* __restrict__ Bp,
             void* outp, const float* __restrict__ bias,
             const void* addp, int M, int N, int K)
{
    __shared__ __attribute__((aligned(16))) bf16_t As0[256 * 64];
    __shared__ __attribute__((aligned(16))) bf16_t As1[256 * 64];
    __shared__ __attribute__((aligned(16))) bf16_t As2[256 * 64];
    __shared__ __attribute__((aligned(16))) bf16_t Bs0[256 * 64];
    __shared__ __attribute__((aligned(16))) bf16_t Bs1[256 * 64];

    const int tid  = threadIdx.x;
    const int w    = tid >> 6, lane = tid & 63;
    const int l16  = lane & 15, lg = lane >> 4;
    const int wm   = w >> 2, wn = w & 3;
    const int srow = lane >> 3;
    const int sslot = lane & 7;

    const int gx  = gridDim.x;
    const int gy  = gridDim.y;
    const int nwg = gx * gy;
    const int bid = blockIdx.y * gx + blockIdx.x;
    const int cpx = nwg >> 3;
    const int sid = (bid & 7) * cpx + (bid >> 3);
    const long m0 = (long)(sid / gy) * 256;
    const long n0 = (long)(sid % gy) * 256;
    const int nkt = K >> 6;

    f32x4 acc[8][4] = {};
    bf16x8 a[4][2], b0[2][2], b1[2][2];

    auto STAGEH = [&](const bf16_t* src, long row0, int kt, bf16_t* dst, int h) {
#pragma unroll
        for (int i = 0; i < 2; ++i) {
            int r  = h * 128 + w * 16 + i * 8 + srow;
            int ss = sslot ^ (r & 7);
            gload_lds16(src + (row0 + r) * (long)K + (long)kt * 64 + ss * 8,
                        dst + (h * 128 + w * 16 + i * 8) * 64);
        }
    };

#define LDA_M(buf, mh) do {                                               \
    _Pragma("unroll") for (int j = 0; j < 4; ++j)                         \
    _Pragma("unroll") for (int kk = 0; kk < 2; ++kk) {                    \
        int r  = wm * 128 + (mh) * 64 + j * 16 + l16;                     \
        int ss = (kk * 4 + lg) ^ (r & 7);                                 \
        a[j][kk] = *(const bf16x8*)&buf[r * 64 + ss * 8];                 \
    } } while (0)

#define LDB_M(dst, buf, nh) do {                                          \
    _Pragma("unroll") for (int n = 0; n < 2; ++n)                         \
    _Pragma("unroll") for (int kk = 0; kk < 2; ++kk) {                    \
        int r  = wn * 64 + ((nh) * 2 + n) * 16 + l16;                     \
        int ss = (kk * 4 + lg) ^ (r & 7);                                 \
        dst[n][kk] = *(const bf16x8*)&buf[r * 64 + ss * 8];               \
    } } while (0)

#define MMA_M(bv, mh, nh) do {                                            \
    __builtin_amdgcn_s_setprio(1);                                        \
    _Pragma("unroll") for (int j = 0; j < 4; ++j)                         \
    _Pragma("unroll") for (int n = 0; n < 2; ++n)                         \
    _Pragma("unroll") for (int kk = 0; kk < 2; ++kk)                      \
        acc[(mh) * 4 + j][(nh) * 2 + n] =                                 \
            __builtin_amdgcn_mfma_f32_16x16x32_bf16(                      \
                a[j][kk], bv[n][kk], acc[(mh) * 4 + j][(nh) * 2 + n],     \
                0, 0, 0);                                                 \
    __builtin_amdgcn_s_setprio(0);                                        \
} while (0)

#define PRE_MFMA() do { __builtin_amdgcn_s_barrier();                     \
    asm volatile("s_waitcnt lgkmcnt(0)" ::: "memory");                    \
    __builtin_amdgcn_sched_barrier(0); } while (0)

    // ---- prologue: A(0)->As0, B(0)->Bs0, A(1)->As1, all landed ----
    STAGEH(Ap, m0, 0, As0, 0); STAGEH(Ap, m0, 0, As0, 1);
    STAGEH(Bp, n0, 0, Bs0, 0); STAGEH(Bp, n0, 0, Bs0, 1);
    STAGEH(Ap, m0, 1, As1, 0); STAGEH(Ap, m0, 1, As1, 1);
    asm volatile("s_waitcnt vmcnt(0)" ::: "memory");
    __builtin_amdgcn_s_barrier();
    __builtin_amdgcn_sched_barrier(0);

    bf16_t *Ar = As0, *An1 = As1, *An2 = As2;
    bf16_t *Br = Bs0, *Bw = Bs1;

    for (int c = 0; c < nkt; ++c) {
        const bool pfa = (c + 2 < nkt);
        const bool pfb = (c + 1 < nkt);

        // P1
        LDA_M(Ar, 0); LDB_M(b0, Br, 0);
        if (pfb) { STAGEH(Bp, n0, c + 1, Bw, 0); STAGEH(Bp, n0, c + 1, Bw, 1); }
        if (pfa) STAGEH(Ap, m0, c + 2, An2, 0);
        PRE_MFMA(); MMA_M(b0, 0, 0); __builtin_amdgcn_s_barrier();
        // P2
        LDB_M(b1, Br, 1);
        PRE_MFMA(); MMA_M(b1, 0, 1); __builtin_amdgcn_s_barrier();
        // P3
        LDA_M(Ar, 1);
        if (pfa) STAGEH(Ap, m0, c + 2, An2, 1);
        PRE_MFMA(); MMA_M(b1, 1, 1); __builtin_amdgcn_s_barrier();
        // P4
        if (pfa) { asm volatile("s_waitcnt vmcnt(4)" ::: "memory"); }
        else     { asm volatile("s_waitcnt vmcnt(0)" ::: "memory"); }
        __builtin_amdgcn_s_barrier();
        __builtin_amdgcn_sched_barrier(0);
        MMA_M(b0, 1, 0); __builtin_amdgcn_s_barrier();

        bf16_t* t = Ar; Ar = An1; An1 = An2; An2 = t;
        t = Br; Br = Bw; Bw = t;
    }

    // ---- epilogue ----
#pragma unroll
    for (int fm = 0; fm < 8; ++fm) {
#pragma unroll
        for (int fn = 0; fn < 4; ++fn) {
            const long gcol = n0 + wn * 64 + fn * 16 + l16;
            float bv = 0.f;
            if (MODE != 0 && MODE != 4) bv = bias[gcol];
            const long grow0 = m0 + wm * 128 + fm * 16 + lg * 4;
            if (MODE == 4 && gcol >= 2048) {
                union { bf16_t h[4]; uint2 u; } pk;
#pragma unroll
                for (int e = 0; e < 4; ++e) pk.h[e] = (bf16_t)acc[fm][fn][e];
                const int hh = (int)(gcol >> 6) - 32;
                const int d  = (int)gcol & 63;
                const long bb = grow0 >> 8;
                const int s0  = (int)grow0 & 255;
                *(uint2*)((bf16_t*)addp + ((bb * 16 + hh) * 64 + d) * 256 + s0) = pk.u;
                continue;
            }
#pragma unroll
            for (int e = 0; e < 4; ++e) {
                const long grow = grow0 + e;
                float v = acc[fm][fn][e];
                if (MODE == 0 || MODE == 4) {
                    ((bf16_t*)outp)[grow * N + gcol] = (bf16_t)v;
                } else if (MODE == 1) {
                    v += bv + ((const float*)addp)[grow * N + gcol];
                    ((float*)outp)[grow * N + gcol] = v;
                } else if (MODE == 2) {
                    v += bv; v = v > 0.f ? v : 0.f;
                    ((bf16_t*)outp)[grow * N + gcol] = (bf16_t)v;
                } else {
                    v += bv + (float)((const bf16_t*)addp)[grow * N + gcol];
                    ((bf16_t*)outp)[grow * N + gcol] = (bf16_t)v;
                }
            }
        }
    }
#undef LDA_M
#undef LDB_M
#undef MMA_M
#undef PRE_MFMA
}

// ---------------- fused causal attention ----------------
// qkv: [B*T, 3072] bf16 (Q cols 0..1023, K cols 1024..2047; V region unused)
// vt:  [B*H, 64, 256] bf16 (V^T, s-contiguous, written by QKV GEMM MODE 4)
// 1 block per (b,h); 4 waves. Causal-balanced: fragment block fm owns rows
// fm*64 + w*16 + [0,16) -> every wave does 10 (st,fm) units. K/V double-buffered.
__global__ __launch_bounds__(256)
void attn_kernel(const bf16_t* __restrict__ qkv, const bf16_t* __restrict__ vt,
                 bf16_t* __restrict__ outp)
{
    __shared__ __attribute__((aligned(16))) bf16_t Kt[2][64 * 64];
    __shared__ __attribute__((aligned(16))) bf16_t Vt[2][64 * 64];
    __shared__ __attribute__((aligned(16))) bf16_t Ps[4][16 * 72];

    const int tid = threadIdx.x, w = tid >> 6, lane = tid & 63;
    const int l16 = lane & 15, lg = lane >> 4;
    const int b = blockIdx.x >> 4, hh = blockIdx.x & 15;
    const bf16_t* pq = qkv + (long)(b * 256) * 3072 + hh * 64;
    const bf16_t* pv = vt + (long)blockIdx.x * 64 * 256;
    const int sr8 = lane >> 3;
    const int sl  = lane & 7;

    // Q fragments: fm block rows = fm*64 + w*16 + l16
    bf16x8 qf[4][2];
#pragma unroll
    for (int fm = 0; fm < 4; ++fm)
#pragma unroll
        for (int kk = 0; kk < 2; ++kk)
            qf[fm][kk] = *(const bf16x8*)(pq + (long)(fm * 64 + w * 16 + l16) * 3072
                                          + kk * 32 + lg * 8);

    f32x4 o[4][4] = {};
    float mrun[4][4], lrun[4][4];
#pragma unroll
    for (int i = 0; i < 4; ++i)
#pragma unroll
        for (int j = 0; j < 4; ++j) { mrun[i][j] = -__builtin_inff(); lrun[i][j] = 0.f; }

    auto STAGE = [&](int st, int bb) {
#pragma unroll
        for (int i = 0; i < 2; ++i) {
            int r  = w * 16 + i * 8 + sr8;
            int ss = sl ^ (r & 7);
            gload_lds16(pq + (long)(st * 64 + r) * 3072 + 1024 + ss * 8,
                        &Kt[bb][(w * 16 + i * 8) * 64]);
            gload_lds16(pv + (long)r * 256 + st * 64 + ss * 8,
                        &Vt[bb][(w * 16 + i * 8) * 64]);
        }
    };

    STAGE(0, 0);
    asm volatile("s_waitcnt vmcnt(0)" ::: "memory");
    __syncthreads();

#pragma unroll
    for (int st = 0; st < 4; ++st) {
        const int cb = st & 1;
        if (st < 3) STAGE(st + 1, cb ^ 1);

        // S = Q K^T for fm >= st
        f32x4 s[4][4] = {};
#pragma unroll
        for (int ks = 0; ks < 2; ++ks) {
            bf16x8 kb[4];
#pragma unroll
            for (int fs = 0; fs < 4; ++fs)
                kb[fs] = *(const bf16x8*)&Kt[cb][(fs * 16 + l16) * 64
                                               + ((ks * 4 + lg) ^ (l16 & 7)) * 8];
#pragma unroll
            for (int fm = 0; fm < 4; ++fm) {
                if (fm < st) continue;
#pragma unroll
                for (int fs = 0; fs < 4; ++fs)
                    s[fm][fs] = __builtin_amdgcn_mfma_f32_16x16x32_bf16(
                        qf[fm][ks], kb[fs], s[fm][fs], 0, 0, 0);
            }
        }

#pragma unroll
        for (int fm = 0; fm < 4; ++fm) {
            if (fm < st) continue;
#pragma unroll
            for (int fs = 0; fs < 4; ++fs)
#pragma unroll
                for (int e = 0; e < 4; ++e) {
                    float v = s[fm][fs][e] * 0.03125f;
                    if (st == fm && (fs * 16 + l16) > (w * 16 + lg * 4 + e))
                        v = -__builtin_inff();
                    s[fm][fs][e] = v;
                }
#pragma unroll
            for (int e = 0; e < 4; ++e) {
                float pm = fmaxf(fmaxf(s[fm][0][e], s[fm][1][e]),
                                 fmaxf(s[fm][2][e], s[fm][3][e]));
#pragma unroll
                for (int off = 1; off < 16; off <<= 1) pm = fmaxf(pm, __shfl_xor(pm, off));
                float mnew  = fmaxf(mrun[fm][e], pm);
                float alpha = __expf(mrun[fm][e] - mnew);
                float rs = 0.f;
#pragma unroll
                for (int fs = 0; fs < 4; ++fs) {
                    float p = __expf(s[fm][fs][e] - mnew);
                    s[fm][fs][e] = p;
                    rs += p;
                }
#pragma unroll
                for (int off = 1; off < 16; off <<= 1) rs += __shfl_xor(rs, off);
                lrun[fm][e] = lrun[fm][e] * alpha + rs;
                mrun[fm][e] = mnew;
#pragma unroll
                for (int fd = 0; fd < 4; ++fd) o[fm][fd][e] *= alpha;
            }
#pragma unroll
            for (int fs = 0; fs < 4; ++fs)
#pragma unroll
                for (int e = 0; e < 4; ++e)
                    Ps[w][(lg * 4 + e) * 72 + fs * 16 + l16] = (bf16_t)s[fm][fs][e];
            bf16x8 ap0 = *(const bf16x8*)&Ps[w][l16 * 72 + lg * 8];
            bf16x8 ap1 = *(const bf16x8*)&Ps[w][l16 * 72 + 32 + lg * 8];
#pragma unroll
            for (int fd = 0; fd < 4; ++fd) {
                bf16x8 vb0 = *(const bf16x8*)&Vt[cb][(fd * 16 + l16) * 64
                                                    + ((lg) ^ (l16 & 7)) * 8];
                bf16x8 vb1 = *(const bf16x8*)&Vt[cb][(fd * 16 + l16) * 64
                                                    + ((4 + lg) ^ (l16 & 7)) * 8];
                o[fm][fd] = __builtin_amdgcn_mfma_f32_16x16x32_bf16(ap0, vb0, o[fm][fd], 0, 0, 0);
                o[fm][fd] = __builtin_amdgcn_mfma_f32_16x16x32_bf16(ap1, vb1, o[fm][fd], 0, 0, 0);
            }
        }
        asm volatile("s_waitcnt vmcnt(0)" ::: "memory");
        __syncthreads();
    }

#pragma unroll
    for (int fm = 0; fm < 4; ++fm)
#pragma unroll
        for (int e = 0; e < 4; ++e) {
            float inv = 1.f / lrun[fm][e];
            long row = (long)b * 256 + fm * 64 + w * 16 + lg * 4 + e;
#pragma unroll
            for (int fd = 0; fd < 4; ++fd)
                outp[row * 1024 + hh * 64 + fd * 16 + l16] =
                    (bf16_t)(o[fm][fd][e] * inv);
        }
}

// ---------------- launch ----------------
extern "C" void kernel_launch(void* const* d_in, const int* in_sizes, int n_in,
                              void* d_out, int out_size, void* d_ws, size_t ws_size,
                              hipStream_t stream)
{
    (void)in_sizes; (void)n_in; (void)out_size; (void)ws_size;
    const float* x      = (const float*)d_in[0];
    const float* wq     = (const float*)d_in[1];
    const float* wk     = (const float*)d_in[2];
    const float* wv     = (const float*)d_in[3];
    const float* w_proj = (const float*)d_in[4];
    const float* b_proj = (const float*)d_in[5];
    const float* w1     = (const float*)d_in[6];
    const float* b1     = (const float*)d_in[7];
    const float* w2     = (const float*)d_in[8];
    const float* b2     = (const float*)d_in[9];
    const float* g1  = (const float*)d_in[10]; const float* be1 = (const float*)d_in[11];
    const float* g2  = (const float*)d_in[12]; const float* be2 = (const float*)d_in[13];
    const float* g3  = (const float*)d_in[14]; const float* be3 = (const float*)d_in[15];

    char* ws = (char*)d_ws;
    bf16_t* wqkv  = (bf16_t*)(ws + 0);           //  6,291,456
    bf16_t* wproj = (bf16_t*)(ws + 6291456);     //  2,097,152
    bf16_t* w1t   = (bf16_t*)(ws + 8388608);     //  8,388,608
    bf16_t* w2t   = (bf16_t*)(ws + 16777216);    //  8,388,608
    bf16_t* h     = (bf16_t*)(ws + 25165824);    // 33,554,432 (LN1 out; attn out; start of u)
    bf16_t* qkv   = (bf16_t*)(ws + 58720256);    // 100,663,296 (V third unused)
    bf16_t* attn  = h;
    bf16_t* u     = h;                           // 134,217,728 over dead h+qkv
    bf16_t* y     = (bf16_t*)(ws + 159383552);   // 33,554,432 (vt before LN2; y after)
    bf16_t* vt    = y;
    float*  x2    = (float*)d_out;
    bf16_t* tbuf  = y;

    const int M = 16384;

    transpose_f32_bf16<<<dim3(16, 16), 256, 0, stream>>>(w_proj, wproj, 1024, 1024);
    transpose_f32_bf16<<<dim3(16, 64), 256, 0, stream>>>(w1, w1t, 4096, 1024);
    transpose_f32_bf16<<<dim3(64, 16), 256, 0, stream>>>(w2, w2t, 1024, 4096);
    pack_qkv_t<<<dim3(16, 48), 256, 0, stream>>>(wq, wk, wv, wqkv);

    // h = LN1(x)
    ln_fwd<<<M, 256, 0, stream>>>(x, g1, be1, h);
    // qkv = h @ Wqkv^T ; V columns written transposed into vt
    gemm_bt<4><<<dim3(64, 12), 512, 0, stream>>>(h, wqkv, qkv, nullptr, vt, M, 3072, 1024);
    // attention
    attn_kernel<<<1024, 256, 0, stream>>>(qkv, vt, attn);
    // x2 = x + attn @ Wproj^T + b_proj   -> d_out (f32)
    gemm_bt<1><<<dim3(64, 4), 512, 0, stream>>>(attn, wproj, x2, b_proj, x, M, 1024, 1024);
    // y = LN2(x2)   (overwrites vt, now dead)
    ln_fwd<<<M, 256, 0, stream>>>(x2, g2, be2, y);
    // u = relu(y @ W1^T + b1)
    gemm_bt<2><<<dim3(64, 16), 512, 0, stream>>>(y, w1t, u, b1, nullptr, M, 4096, 1024);
    // tbuf = y + (u @ W2^T + b2)
    gemm_bt<3><<<dim3(64, 4), 512, 0, stream>>>(u, w2t, tbuf, b2, y, M, 1024, 4096);
    // d_out = x2 + LN3(tbuf)
    ln3_kernel<<<M, 256, 0, stream>>>(tbuf, g3, be3, (float*)d_out, x2);
}